// Round 5
// baseline (1149.390 us; speedup 1.0000x reference)
//
#include <hip/hip_runtime.h>

typedef unsigned int uint;
typedef unsigned short ushort;
typedef _Float16 f16;
typedef _Float16 h8 __attribute__((ext_vector_type(8)));
typedef float f32x4 __attribute__((ext_vector_type(4)));

// B=16 L=512 H=12 d=64 D=768 N3=2304 C=20 M=8192

__device__ __forceinline__ float b2f(ushort u){ return __uint_as_float(((uint)u)<<16); }
__device__ __forceinline__ ushort f2b(float f){
  uint u = __float_as_uint(f);
  uint r = u + 0x7fffu + ((u>>16)&1u);
  return (ushort)(r>>16);
}
__device__ __forceinline__ float leaky(float x){ return x >= 0.f ? x : 0.01f*x; }
__device__ __forceinline__ float ldf(const void* p, int idx, int isb){
  return isb ? b2f(((const ushort*)p)[idx]) : ((const float*)p)[idx];
}

// ---------- K-1: detect whether float tensors arrived as bf16 (1) or f32 (0) ----------
__global__ void k_detect(const ushort* __restrict__ wvbits, int* __restrict__ flag){
  if (blockIdx.x==0 && threadIdx.x==0){
    int sane = 0;
    for (int i=0;i<128;i++){
      uint e = (wvbits[i]>>7)&0xffu;
      if (e==0u || (e>=90u && e<=150u)) sane++;
    }
    *flag = (sane >= 115) ? 1 : 0;
  }
}

// ---------- K-0: zero colsum (32x256) and lsum (384x256) ----------
__global__ __launch_bounds__(256) void k_zero(float* __restrict__ colsum,
    float* __restrict__ lsum){
  int bid = blockIdx.x, tid = threadIdx.x;
  if (bid < 32) colsum[bid*256 + tid] = 0.f;
  else          lsum[(bid-32)*256 + tid] = 0.f;
}

// ---------- K0: Ah[m,k] = leaky(emb[ids[m],k])  (fp16 out, KP=768) ----------
__global__ __launch_bounds__(256) void k_build_x(const int* __restrict__ ids,
    const void* __restrict__ emb, f16* __restrict__ Ah, const int* __restrict__ flag){
  int isb = *flag;
  int t = blockIdx.x*256 + threadIdx.x;
  int m = t / 96;
  int kk = (t % 96) * 8;
  float o[8];
  if (isb){
    const ushort* src = (const ushort*)emb + (size_t)ids[m]*768 + kk;
    uint4 v = *(const uint4*)src;
    o[0]=__uint_as_float((v.x&0xffffu)<<16); o[1]=__uint_as_float(v.x&0xffff0000u);
    o[2]=__uint_as_float((v.y&0xffffu)<<16); o[3]=__uint_as_float(v.y&0xffff0000u);
    o[4]=__uint_as_float((v.z&0xffffu)<<16); o[5]=__uint_as_float(v.z&0xffff0000u);
    o[6]=__uint_as_float((v.w&0xffffu)<<16); o[7]=__uint_as_float(v.w&0xffff0000u);
  } else {
    const float* src = (const float*)emb + (size_t)ids[m]*768 + kk;
    float4 v0 = ((const float4*)src)[0];
    float4 v1 = ((const float4*)src)[1];
    o[0]=v0.x; o[1]=v0.y; o[2]=v0.z; o[3]=v0.w;
    o[4]=v1.x; o[5]=v1.y; o[6]=v1.z; o[7]=v1.w;
  }
  h8 hv;
  #pragma unroll
  for (int i=0;i<8;i++) hv[i] = (f16)leaky(o[i]);
  *(h8*)(Ah + (size_t)m*768 + kk) = hv;
}

// ---------- K0b: generic fp16 repack with zero-pad: dst[n,KP] from src[n,Ksrc] ----------
__global__ __launch_bounds__(256) void k_prep(const void* __restrict__ src,
    f16* __restrict__ dst, int Ksrc, int kp8, const int* __restrict__ flag){
  int isb = *flag;
  int t = blockIdx.x*256 + threadIdx.x;
  int n = t / kp8;
  int kk = (t % kp8) * 8;
  h8 hv;
  #pragma unroll
  for (int i=0;i<8;i++){
    int k = kk + i;
    hv[i] = (k < Ksrc) ? (f16)ldf(src, n*Ksrc + k, isb) : (f16)0.f;
  }
  *(h8*)(dst + (size_t)n*(kp8*8) + kk) = hv;
}

// ---------- K1: MFMA QKV GEMM + fused Q/K row-normalize ----------
// Per wave 64x64 output (4x4 frags of 16x16x32), A/B direct from global, reg dbuf.
// Q,K normalized over d=64 in-epilogue (full d-row lives in the wave's tile).
template<int KP>
__global__ __launch_bounds__(256) void k_gemm_mfma(const f16* __restrict__ Ah,
    const f16* __restrict__ Wh, const void* __restrict__ bias, const int* __restrict__ flag,
    f16* __restrict__ Qh, f16* __restrict__ Kh, f16* __restrict__ Vt){
  constexpr int STEPS = KP/32;
  int tid = threadIdx.x;
  int w = tid >> 6, lane = tid & 63;
  int mrow = lane & 15, kq = lane >> 4;
  int m0 = blockIdx.x * 64;
  int n0 = blockIdx.y * 256 + w * 64;

  const f16* ap = Ah + (size_t)(m0 + mrow)*KP + kq*8;
  const f16* bp = Wh + (size_t)(n0 + mrow)*KP + kq*8;

  f32x4 acc[4][4];
  #pragma unroll
  for (int mt=0; mt<4; mt++)
    #pragma unroll
    for (int nt=0; nt<4; nt++) acc[mt][nt] = (f32x4){0.f,0.f,0.f,0.f};

  h8 a0[4], b0[4], a1[4], b1[4];
#define LOADA(buf, step) { const f16* p_ = ap + (step)*32; \
  buf[0]=*(const h8*)(p_); buf[1]=*(const h8*)(p_+(size_t)16*KP); \
  buf[2]=*(const h8*)(p_+(size_t)32*KP); buf[3]=*(const h8*)(p_+(size_t)48*KP); }
#define LOADB(buf, step) { const f16* p_ = bp + (step)*32; \
  buf[0]=*(const h8*)(p_); buf[1]=*(const h8*)(p_+(size_t)16*KP); \
  buf[2]=*(const h8*)(p_+(size_t)32*KP); buf[3]=*(const h8*)(p_+(size_t)48*KP); }
#define MM(A_, B_) { \
  _Pragma("unroll") for (int mt=0; mt<4; mt++) \
    _Pragma("unroll") for (int nt=0; nt<4; nt++) \
      acc[mt][nt] = __builtin_amdgcn_mfma_f32_16x16x32_f16(A_[mt], B_[nt], acc[mt][nt], 0, 0, 0); }

  LOADA(a0, 0); LOADB(b0, 0);
  #pragma unroll
  for (int ks=0; ks<STEPS; ks+=2){
    LOADA(a1, ks+1); LOADB(b1, ks+1);
    MM(a0, b0);
    if (ks+2 < STEPS){ LOADA(a0, ks+2); LOADB(b0, ks+2); }
    MM(a1, b1);
  }
#undef LOADA
#undef LOADB
#undef MM

  int isb = *flag;
  int s = n0 / 768;
  int h = (n0 % 768) >> 6;
  float bv[4];
  #pragma unroll
  for (int nt=0; nt<4; nt++) bv[nt] = ldf(bias, n0 + nt*16 + mrow, isb);

  #pragma unroll
  for (int mt=0; mt<4; mt++){
    float yv[4][4];   // [nt][r]
    #pragma unroll
    for (int nt=0; nt<4; nt++)
      #pragma unroll
      for (int r=0; r<4; r++)
        yv[nt][r] = leaky(acc[mt][nt][r] + bv[nt]);
    if (s < 2){
      #pragma unroll
      for (int r=0; r<4; r++){
        float ss = yv[0][r]*yv[0][r] + yv[1][r]*yv[1][r]
                 + yv[2][r]*yv[2][r] + yv[3][r]*yv[3][r];
        ss += __shfl_xor(ss, 1); ss += __shfl_xor(ss, 2);
        ss += __shfl_xor(ss, 4); ss += __shfl_xor(ss, 8);
        float rn = 1.f / fmaxf(sqrtf(ss), 1e-8f);
        #pragma unroll
        for (int nt=0; nt<4; nt++) yv[nt][r] *= rn;
      }
    }
    #pragma unroll
    for (int nt=0; nt<4; nt++){
      #pragma unroll
      for (int r=0; r<4; r++){
        int m = m0 + mt*16 + kq*4 + r;
        int dd = nt*16 + mrow;
        int bq = m >> 9, l = m & 511;
        float y = yv[nt][r];
        if (s == 0)      Qh[((size_t)(bq*12 + h)*512 + l)*64 + dd] = (f16)y;
        else if (s == 1) Kh[((size_t)(bq*12 + h)*512 + l)*64 + dd] = (f16)y;
        else             Vt[((size_t)(bq*12 + h)*64 + dd)*512 + l] = (f16)y;
      }
    }
  }
}

// ---------- K3a: scores -> head-LN -> exp (ONCE) -> E (fp16, [b,h,i,j]) + rowsum partials ----------
// grid = b(16) x itile(32) x jtile(16) = 8192 blocks
__global__ __launch_bounds__(256) void k_scores(const f16* __restrict__ Qh,
    const f16* __restrict__ Kh, const void* __restrict__ gamma,
    const void* __restrict__ beta, const int* __restrict__ flag,
    f16* __restrict__ E, float* __restrict__ lsum){
  constexpr int ZS = 402;   // f32 words per i-row (12*33=396, pad to ==2 mod 8: 2-way-free C-scatter)
  constexpr int TS = 40;    // zt halves per (h,i) row (16B aligned)
  __shared__ float z[16*ZS];          // [i][h*33 + j]
  __shared__ f16   zt[12*16*TS];      // [h][i][j]
  __shared__ float gL[12], beL[12];

  int tid = threadIdx.x;
  int w = tid >> 6, lane = tid & 63;
  int kq = lane >> 4, mrow = lane & 15;
  int bx = blockIdx.x;
  int jt = bx & 15, it = (bx >> 4) & 31, b = bx >> 9;
  int i0 = it*16, j0 = jt*32;

  if (tid < 12){ int isb = *flag; gL[tid] = ldf(gamma, tid, isb); beL[tid] = ldf(beta, tid, isb); }

  // QK^T: 16i x 32j for this wave's 3 heads
  #pragma unroll
  for (int hh=0; hh<3; hh++){
    int h = w*3 + hh;
    const f16* kb = Kh + ((size_t)(b*12+h)*512 + i0 + mrow)*64;
    h8 a0 = *(const h8*)(kb + kq*8);
    h8 a1 = *(const h8*)(kb + 32 + kq*8);
    const f16* qb = Qh + ((size_t)(b*12+h)*512 + j0)*64;
    #pragma unroll
    for (int jn=0; jn<2; jn++){
      const f16* qr = qb + (size_t)(jn*16 + mrow)*64;
      h8 q0 = *(const h8*)(qr + kq*8);
      h8 q1 = *(const h8*)(qr + 32 + kq*8);
      f32x4 c = (f32x4){0.f,0.f,0.f,0.f};
      c = __builtin_amdgcn_mfma_f32_16x16x32_f16(a0, q0, c, 0, 0, 0);
      c = __builtin_amdgcn_mfma_f32_16x16x32_f16(a1, q1, c, 0, 0, 0);
      #pragma unroll
      for (int r=0;r<4;r++)
        z[(kq*4 + r)*ZS + h*33 + jn*16 + mrow] = c[r];
    }
  }
  __syncthreads();
  // LN over heads + exp, write e to zt
  int pj = tid & 31, piw = tid >> 5;   // piw 0..7
  #pragma unroll
  for (int p=0; p<2; p++){
    int i = piw + p*8;
    float s[12];
    float mu = 0.f, sq = 0.f;
    #pragma unroll
    for (int h=0;h<12;h++){ s[h] = z[i*ZS + h*33 + pj]; mu += s[h]; sq += s[h]*s[h]; }
    mu *= (1.f/12.f);
    float var = fmaxf(sq*(1.f/12.f) - mu*mu, 0.f);
    float rstd = rsqrtf(var + 1e-5f);
    #pragma unroll
    for (int h=0;h<12;h++){
      float e = __expf((s[h]-mu)*rstd*gL[h] + beL[h]);
      zt[(h*16 + i)*TS + pj] = (f16)e;
    }
  }
  __syncthreads();
  // rowsum partials: thread t<192 sums its (h,i) row over 32 j
  if (tid < 192){
    int h = tid >> 4, i = tid & 15;
    const f16* zr = &zt[(h*16 + i)*TS];
    float ssum = 0.f;
    #pragma unroll
    for (int q=0;q<4;q++){
      h8 v = *(const h8*)(zr + q*8);
      #pragma unroll
      for (int t=0;t<8;t++) ssum += (float)v[t];
    }
    atomicAdd(&lsum[(size_t)(b*12+h)*512 + i0 + i], ssum);
  }
  // E copy-out: 768 h8-units, 3 per thread, coalesced
  #pragma unroll
  for (int u0=0; u0<3; u0++){
    int u = tid + u0*256;
    int h = u >> 6, rem = u & 63, i = rem >> 2, q = rem & 3;
    h8 v = *(const h8*)&zt[(h*16 + i)*TS + q*8];
    *(h8*)(E + ((size_t)(b*12+h)*512 + i0 + i)*512 + j0 + q*8) = v;
  }
}

// ---------- K3b: PV MFMA from E + fused colsum; O scaled by 1/l. No LDS, no barriers. ----------
// grid = b(16) x itile(32) = 512 blocks
__global__ __launch_bounds__(256) void k_pv(const f16* __restrict__ E,
    const f16* __restrict__ Vt, const float* __restrict__ lsum,
    float* __restrict__ O, float* __restrict__ colsum){
  int tid = threadIdx.x;
  int w = tid >> 6, lane = tid & 63;
  int kq = lane >> 4, mrow = lane & 15;
  int bx = blockIdx.x;
  int b = bx >> 5, it = bx & 31, i0 = it*16;

  f32x4 oacc[3][4];
  #pragma unroll
  for (int hh=0; hh<3; hh++)
    #pragma unroll
    for (int nt=0; nt<4; nt++) oacc[hh][nt] = (f32x4){0.f,0.f,0.f,0.f};

  float gcs[3];
  #pragma unroll
  for (int hh=0; hh<3; hh++)
    gcs[hh] = 1.f / lsum[(size_t)(b*12 + w*3 + hh)*512 + i0 + mrow];

  for (int jt=0; jt<16; jt++){
    float acc8[8];
    #pragma unroll
    for (int t=0;t<8;t++) acc8[t] = 0.f;
    #pragma unroll
    for (int hh=0; hh<3; hh++){
      int h = w*3 + hh;
      h8 ea = *(const h8*)(E + ((size_t)(b*12+h)*512 + i0 + mrow)*512 + jt*32 + kq*8);
      const f16* vb = Vt + ((size_t)(b*12+h)*64)*512;
      #pragma unroll
      for (int nt=0; nt<4; nt++){
        h8 bf = *(const h8*)(vb + (size_t)(nt*16 + mrow)*512 + jt*32 + kq*8);
        oacc[hh][nt] = __builtin_amdgcn_mfma_f32_16x16x32_f16(ea, bf, oacc[hh][nt], 0, 0, 0);
      }
      #pragma unroll
      for (int t=0;t<8;t++) acc8[t] += (float)ea[t] * gcs[hh];
    }
    // reduce over the 16 mrow lanes (i) within each kq group
    #pragma unroll
    for (int t=0;t<8;t++){
      acc8[t] += __shfl_xor(acc8[t], 1); acc8[t] += __shfl_xor(acc8[t], 2);
      acc8[t] += __shfl_xor(acc8[t], 4); acc8[t] += __shfl_xor(acc8[t], 8);
    }
    if (mrow == 0){
      int jb = b*512 + jt*32 + kq*8;
      #pragma unroll
      for (int t=0;t<8;t++) atomicAdd(&colsum[jb + t], acc8[t]*(1.f/12.f));
    }
  }
  // epilogue: O = oacc / l
  #pragma unroll
  for (int hh=0; hh<3; hh++){
    int h = w*3 + hh;
    #pragma unroll
    for (int r=0;r<4;r++){
      float g = 1.f / lsum[(size_t)(b*12+h)*512 + i0 + kq*4 + r];
      #pragma unroll
      for (int nt=0; nt<4; nt++)
        O[((size_t)(b*512) + i0 + kq*4 + r)*768 + h*64 + nt*16 + mrow] = oacc[hh][nt][r] * g;
    }
  }
}

// ---------- K3 (fallback, small ws): fused attention, two-sweep ----------
__global__ __launch_bounds__(256) void k_attn2(const f16* __restrict__ Qh,
    const f16* __restrict__ Kh, const f16* __restrict__ Vt,
    const void* __restrict__ gamma, const void* __restrict__ beta,
    const int* __restrict__ flag,
    float* __restrict__ O, float* __restrict__ colsum){
  constexpr int ZS = 421;
  constexpr int TS = 40;
  __shared__ float z[16*ZS];
  __shared__ f16   zt[12*16*TS];
  __shared__ float rsL[192];
  __shared__ float csL[32];
  __shared__ float gL[12], beL[12];

  int tid = threadIdx.x;
  int w = tid >> 6, lane = tid & 63;
  int kq = lane >> 4, mrow = lane & 15;
  int bx = blockIdx.x;
  int b = bx >> 5, i0 = (bx & 31) << 4;
  int pj = tid & 31, pi = tid >> 5;

  if (tid < 12){ int isb = *flag; gL[tid] = ldf(gamma, tid, isb); beL[tid] = ldf(beta, tid, isb); }
  if (tid < 32) csL[tid] = 0.f;

  h8 ak[3][2];
  #pragma unroll
  for (int hh=0; hh<3; hh++){
    int h = w*3 + hh;
    const f16* kb = Kh + ((size_t)(b*12+h)*512 + i0 + mrow)*64;
    #pragma unroll
    for (int ks=0; ks<2; ks++)
      ak[hh][ks] = *(const h8*)(kb + ks*32 + kq*8);
  }
  f32x4 oacc[3][4];
  #pragma unroll
  for (int hh=0; hh<3; hh++)
    #pragma unroll
    for (int nt=0; nt<4; nt++)
      oacc[hh][nt] = (f32x4){0.f,0.f,0.f,0.f};
  float racc[2][12];
  #pragma unroll
  for (int p=0;p<2;p++)
    #pragma unroll
    for (int h=0;h<12;h++) racc[p][h] = 0.f;

  __syncthreads();

  for (int sweep=0; sweep<2; sweep++){
    for (int jt=0; jt<16; jt++){
      #pragma unroll
      for (int hh=0; hh<3; hh++){
        int h = w*3 + hh;
        const f16* qb = Qh + ((size_t)(b*12+h)*512 + jt*32)*64;
        #pragma unroll
        for (int jn=0; jn<2; jn++){
          f32x4 c = (f32x4){0.f,0.f,0.f,0.f};
          #pragma unroll
          for (int ks=0; ks<2; ks++){
            h8 bf = *(const h8*)(qb + (size_t)(jn*16 + mrow)*64 + ks*32 + kq*8);
            c = __builtin_amdgcn_mfma_f32_16x16x32_f16(ak[hh][ks], bf, c, 0, 0, 0);
          }
          int jl = jn*16 + mrow;
          #pragma unroll
          for (int r=0;r<4;r++)
            z[(kq*4 + r)*ZS + jl*13 + h] = c[r];
        }
      }
      __syncthreads();
      #pragma unroll
      for (int p=0; p<2; p++){
        int i = pi + p*8, j = pj;
        const float* zp = &z[i*ZS + j*13];
        float s[12];
        float mu = 0.f, sq = 0.f;
        #pragma unroll
        for (int h=0;h<12;h++){ s[h] = zp[h]; mu += s[h]; sq += s[h]*s[h]; }
        mu *= (1.f/12.f);
        float var = fmaxf(sq*(1.f/12.f) - mu*mu, 0.f);
        float rstd = rsqrtf(var + 1e-5f);
        if (sweep == 0){
          #pragma unroll
          for (int h=0;h<12;h++){
            float e = __expf((s[h]-mu)*rstd*gL[h] + beL[h]);
            racc[p][h] += e;
          }
        } else {
          float cacc = 0.f;
          #pragma unroll
          for (int h=0;h<12;h++){
            float e = __expf((s[h]-mu)*rstd*gL[h] + beL[h]);
            zt[(h*16 + i)*TS + j] = (f16)e;
            cacc += e * rsL[h*16 + i];
          }
          atomicAdd(&csL[j], cacc*(1.f/12.f));
        }
      }
      if (sweep == 0){
        __syncthreads();
      } else {
        __syncthreads();
        #pragma unroll
        for (int hh=0; hh<3; hh++){
          int h = w*3 + hh;
          h8 pa = *(const h8*)&zt[(h*16 + mrow)*TS + kq*8];
          const f16* vb = Vt + ((size_t)(b*12+h)*64)*512;
          #pragma unroll
          for (int nt=0; nt<4; nt++){
            h8 bf = *(const h8*)(vb + (size_t)(nt*16 + mrow)*512 + jt*32 + kq*8);
            oacc[hh][nt] = __builtin_amdgcn_mfma_f32_16x16x32_f16(pa, bf, oacc[hh][nt], 0, 0, 0);
          }
        }
        if (tid < 32){
          atomicAdd(&colsum[b*512 + jt*32 + tid], csL[tid]);
          csL[tid] = 0.f;
        }
      }
    }
    if (sweep == 0){
      #pragma unroll
      for (int p=0;p<2;p++){
        #pragma unroll
        for (int h=0;h<12;h++){
          float v = racc[p][h];
          #pragma unroll
          for (int m=1; m<32; m<<=1) v += __shfl_xor(v, m);
          if ((lane & 31) == 0) rsL[h*16 + (pi + p*8)] = 1.f / v;
        }
      }
      __syncthreads();
    }
  }
  #pragma unroll
  for (int hh=0; hh<3; hh++){
    int h = w*3 + hh;
    #pragma unroll
    for (int nt=0; nt<4; nt++){
      #pragma unroll
      for (int r=0;r<4;r++){
        int i = kq*4 + r;
        float val = oacc[hh][nt][r] * rsL[h*16 + i];
        O[((size_t)(b*512) + i0 + i)*768 + h*64 + nt*16 + mrow] = val;
      }
    }
  }
}

// ---------- K4: probs[m,:] = softmax(O[m,:] @ Wout^T + bout) ----------
__global__ __launch_bounds__(256) void k_probs(const float* __restrict__ O,
    const void* __restrict__ Wout, const void* __restrict__ bout,
    const int* __restrict__ flag, float* __restrict__ probs){
  int isb = *flag;
  int tid = threadIdx.x, wv = tid>>6, lane = tid&63;
  int m = blockIdx.x*4 + wv;
  const float* orow = O + (size_t)m*768;
  float acc[20];
  #pragma unroll
  for (int c=0;c<20;c++) acc[c]=0.f;
  for (int kk=0; kk<12; kk++){
    float o = orow[kk*64 + lane];
    #pragma unroll
    for (int c=0;c<20;c++)
      acc[c] += o * ldf(Wout, c*768 + kk*64 + lane, isb);
  }
  #pragma unroll
  for (int c=0;c<20;c++){
    #pragma unroll
    for (int off=1; off<64; off<<=1) acc[c] += __shfl_xor(acc[c], off, 64);
  }
  float mx = -3.4e38f;
  #pragma unroll
  for (int c=0;c<20;c++){ acc[c] += ldf(bout, c, isb); mx = fmaxf(mx, acc[c]); }
  float s=0.f;
  #pragma unroll
  for (int c=0;c<20;c++){ acc[c] = __expf(acc[c]-mx); s += acc[c]; }
  float inv = 1.f/s;
  if (lane == 0){
    float* pr = probs + (size_t)m*20;
    #pragma unroll
    for (int c=0;c<20;c++) pr[c] = acc[c]*inv;
  }
}

// ---------- K5: weights = softmax(mask*colsum); out[b,:] = sum_l w[l]*probs[b,l,:] ----------
__global__ __launch_bounds__(512) void k_final(const int* __restrict__ ids,
    const float* __restrict__ colsum, const float* __restrict__ probs,
    const int* __restrict__ flag,
    float* __restrict__ accb, void* __restrict__ outp, int br){
  __shared__ float red[8];
  __shared__ float bcast;
  __shared__ float pacc[8][20];
  int b = blockIdx.x, tid = threadIdx.x;
  int wv = tid>>6, lane = tid&63;
  float w = (ids[b*512+tid] != 0) ? colsum[b*512+tid] : 0.f;
  float mx = w;
  #pragma unroll
  for (int off=1; off<64; off<<=1) mx = fmaxf(mx, __shfl_xor(mx, off, 64));
  if (lane==0) red[wv] = mx;
  __syncthreads();
  if (tid==0){ float m2 = red[0]; for (int k2=1;k2<8;k2++) m2 = fmaxf(m2, red[k2]); bcast = m2; }
  __syncthreads();
  float M = bcast;
  float e = __expf(w - M);
  float s = e;
  #pragma unroll
  for (int off=1; off<64; off<<=1) s += __shfl_xor(s, off, 64);
  if (lane==0) red[wv] = s;
  __syncthreads();
  if (tid==0){ float s2=0.f; for (int k2=0;k2<8;k2++) s2 += red[k2]; bcast = s2; }
  __syncthreads();
  float wn = e / bcast;
  float p[20];
  const float* pr = probs + ((size_t)b*512 + tid)*20;
  #pragma unroll
  for (int c=0;c<20;c++) p[c] = wn * pr[c];
  #pragma unroll
  for (int c=0;c<20;c++){
    #pragma unroll
    for (int off=1; off<64; off<<=1) p[c] += __shfl_xor(p[c], off, 64);
  }
  if (lane==0){
    #pragma unroll
    for (int c=0;c<20;c++) pacc[wv][c] = p[c];
  }
  __syncthreads();
  if (tid < 20){
    float s2 = 0.f;
    #pragma unroll
    for (int k2=0;k2<8;k2++) s2 += pacc[k2][tid];
    if (br == 0) accb[b*20 + tid] = s2;
    else {
      float v = (accb[b*20 + tid] + s2) * 0.5f;
      if (*flag) ((ushort*)outp)[b*20 + tid] = f2b(v);
      else       ((float*)outp)[b*20 + tid] = v;
    }
  }
}

extern "C" void kernel_launch(void* const* d_in, const int* in_sizes, int n_in,
                              void* d_out, int out_size, void* d_ws, size_t ws_size,
                              hipStream_t stream){
  (void)in_sizes; (void)n_in; (void)out_size;
  const int*  ids = (const int*)d_in[0];
  const void* wvp = d_in[1];
  const void* emb = d_in[2];
  const void* Wt[2]  = {d_in[3], d_in[9]};
  const void* bt[2]  = {d_in[4], d_in[10]};
  const void* gm[2]  = {d_in[5], d_in[11]};
  const void* bet[2] = {d_in[6], d_in[12]};
  const void* Wo[2]  = {d_in[7], d_in[13]};
  const void* bo[2]  = {d_in[8], d_in[14]};

  float*  O      = (float*)d_ws;            // 6291456 f32
  f16*    Qh     = (f16*)(O + 6291456);     // 6291456 f16
  f16*    Kh     = Qh + 6291456;            // 6291456 f16
  f16*    Vt     = Kh + 6291456;            // 6291456 f16
  f16*    Ah     = Vt + 6291456;            // 6291456 f16
  f16*    Wh     = Ah + 6291456;            // 1769472 f16
  float*  probsb = (float*)(Wh + 1769472);  // 163840 f32
  float*  colsum = probsb + 163840;         // 8192 f32
  float*  accb   = colsum + 8192;           // 320 f32
  int*    flagp  = (int*)(accb + 320);      // 4 ints (pad)
  float*  lsum   = (float*)(flagp + 4);     // 98304 f32
  f16*    E      = (f16*)(lsum + 98304);    // 50331648 f16 (100.7 MB, optional)
  size_t  need   = (size_t)((char*)(E + 50331648) - (char*)d_ws);
  int bigws = (ws_size >= need);

  k_detect<<<1, 64, 0, stream>>>((const ushort*)wvp, flagp);

  for (int br=0; br<2; br++){
    if (br==0){
      k_build_x<<<3072, 256, 0, stream>>>(ids, emb, Ah, flagp);
      k_prep<<<864, 256, 0, stream>>>(Wt[0], Wh, 768, 96, flagp);
    } else {
      k_prep<<<1280, 256, 0, stream>>>(wvp, Ah, 300, 40, flagp);
      k_prep<<<360, 256, 0, stream>>>(Wt[1], Wh, 300, 40, flagp);
    }
    k_zero<<<416, 256, 0, stream>>>(colsum, lsum);
    dim3 g1(128, 9);
    if (br==0) k_gemm_mfma<768><<<g1, 256, 0, stream>>>(Ah, Wh, bt[0], flagp, Qh, Kh, Vt);
    else       k_gemm_mfma<320><<<g1, 256, 0, stream>>>(Ah, Wh, bt[1], flagp, Qh, Kh, Vt);
    if (bigws){
      k_scores<<<8192, 256, 0, stream>>>(Qh, Kh, gm[br], bet[br], flagp, E, lsum);
      k_pv<<<512, 256, 0, stream>>>(E, Vt, lsum, O, colsum);
    } else {
      k_attn2<<<512, 256, 0, stream>>>(Qh, Kh, Vt, gm[br], bet[br], flagp, O, colsum);
    }
    k_probs<<<2048, 256, 0, stream>>>(O, Wo[br], bo[br], flagp, probsb);
    k_final<<<16, 512, 0, stream>>>(ids, colsum, probsb, flagp, accb, d_out, br);
  }
}

// Round 6
// 741.880 us; speedup vs baseline: 1.5493x; 1.5493x over previous
//
#include <hip/hip_runtime.h>

typedef unsigned int uint;
typedef unsigned short ushort;
typedef _Float16 f16;
typedef _Float16 h8 __attribute__((ext_vector_type(8)));
typedef float f32x4 __attribute__((ext_vector_type(4)));

// B=16 L=512 H=12 d=64 D=768 N3=2304 C=20 M=8192

__device__ __forceinline__ float b2f(ushort u){ return __uint_as_float(((uint)u)<<16); }
__device__ __forceinline__ ushort f2b(float f){
  uint u = __float_as_uint(f);
  uint r = u + 0x7fffu + ((u>>16)&1u);
  return (ushort)(r>>16);
}
__device__ __forceinline__ float leaky(float x){ return x >= 0.f ? x : 0.01f*x; }
__device__ __forceinline__ float ldf(const void* p, int idx, int isb){
  return isb ? b2f(((const ushort*)p)[idx]) : ((const float*)p)[idx];
}

// ---------- K-1: detect whether float tensors arrived as bf16 (1) or f32 (0) ----------
__global__ void k_detect(const ushort* __restrict__ wvbits, int* __restrict__ flag){
  if (blockIdx.x==0 && threadIdx.x==0){
    int sane = 0;
    for (int i=0;i<128;i++){
      uint e = (wvbits[i]>>7)&0xffu;
      if (e==0u || (e>=90u && e<=150u)) sane++;
    }
    *flag = (sane >= 115) ? 1 : 0;
  }
}

// ---------- K-0: zero colsum (32x256) and lsum (384x256) ----------
__global__ __launch_bounds__(256) void k_zero(float* __restrict__ colsum,
    float* __restrict__ lsum){
  int bid = blockIdx.x, tid = threadIdx.x;
  if (bid < 32) colsum[bid*256 + tid] = 0.f;
  else          lsum[(bid-32)*256 + tid] = 0.f;
}

// ---------- K0: Ah[m,k] = leaky(emb[ids[m],k])  (fp16 out, KP=768) ----------
__global__ __launch_bounds__(256) void k_build_x(const int* __restrict__ ids,
    const void* __restrict__ emb, f16* __restrict__ Ah, const int* __restrict__ flag){
  int isb = *flag;
  int t = blockIdx.x*256 + threadIdx.x;
  int m = t / 96;
  int kk = (t % 96) * 8;
  float o[8];
  if (isb){
    const ushort* src = (const ushort*)emb + (size_t)ids[m]*768 + kk;
    uint4 v = *(const uint4*)src;
    o[0]=__uint_as_float((v.x&0xffffu)<<16); o[1]=__uint_as_float(v.x&0xffff0000u);
    o[2]=__uint_as_float((v.y&0xffffu)<<16); o[3]=__uint_as_float(v.y&0xffff0000u);
    o[4]=__uint_as_float((v.z&0xffffu)<<16); o[5]=__uint_as_float(v.z&0xffff0000u);
    o[6]=__uint_as_float((v.w&0xffffu)<<16); o[7]=__uint_as_float(v.w&0xffff0000u);
  } else {
    const float* src = (const float*)emb + (size_t)ids[m]*768 + kk;
    float4 v0 = ((const float4*)src)[0];
    float4 v1 = ((const float4*)src)[1];
    o[0]=v0.x; o[1]=v0.y; o[2]=v0.z; o[3]=v0.w;
    o[4]=v1.x; o[5]=v1.y; o[6]=v1.z; o[7]=v1.w;
  }
  h8 hv;
  #pragma unroll
  for (int i=0;i<8;i++) hv[i] = (f16)leaky(o[i]);
  *(h8*)(Ah + (size_t)m*768 + kk) = hv;
}

// ---------- K0b: generic fp16 repack with zero-pad: dst[n,KP] from src[n,Ksrc] ----------
__global__ __launch_bounds__(256) void k_prep(const void* __restrict__ src,
    f16* __restrict__ dst, int Ksrc, int kp8, const int* __restrict__ flag){
  int isb = *flag;
  int t = blockIdx.x*256 + threadIdx.x;
  int n = t / kp8;
  int kk = (t % kp8) * 8;
  h8 hv;
  #pragma unroll
  for (int i=0;i<8;i++){
    int k = kk + i;
    hv[i] = (k < Ksrc) ? (f16)ldf(src, n*Ksrc + k, isb) : (f16)0.f;
  }
  *(h8*)(dst + (size_t)n*(kp8*8) + kk) = hv;
}

// ---------- K1: MFMA QKV GEMM + fused Q/K row-normalize ----------
template<int KP>
__global__ __launch_bounds__(256) void k_gemm_mfma(const f16* __restrict__ Ah,
    const f16* __restrict__ Wh, const void* __restrict__ bias, const int* __restrict__ flag,
    f16* __restrict__ Qh, f16* __restrict__ Kh, f16* __restrict__ Vt){
  constexpr int STEPS = KP/32;
  int tid = threadIdx.x;
  int w = tid >> 6, lane = tid & 63;
  int mrow = lane & 15, kq = lane >> 4;
  int m0 = blockIdx.x * 64;
  int n0 = blockIdx.y * 256 + w * 64;

  const f16* ap = Ah + (size_t)(m0 + mrow)*KP + kq*8;
  const f16* bp = Wh + (size_t)(n0 + mrow)*KP + kq*8;

  f32x4 acc[4][4];
  #pragma unroll
  for (int mt=0; mt<4; mt++)
    #pragma unroll
    for (int nt=0; nt<4; nt++) acc[mt][nt] = (f32x4){0.f,0.f,0.f,0.f};

  h8 a0[4], b0[4], a1[4], b1[4];
#define LOADA(buf, step) { const f16* p_ = ap + (step)*32; \
  buf[0]=*(const h8*)(p_); buf[1]=*(const h8*)(p_+(size_t)16*KP); \
  buf[2]=*(const h8*)(p_+(size_t)32*KP); buf[3]=*(const h8*)(p_+(size_t)48*KP); }
#define LOADB(buf, step) { const f16* p_ = bp + (step)*32; \
  buf[0]=*(const h8*)(p_); buf[1]=*(const h8*)(p_+(size_t)16*KP); \
  buf[2]=*(const h8*)(p_+(size_t)32*KP); buf[3]=*(const h8*)(p_+(size_t)48*KP); }
#define MM(A_, B_) { \
  _Pragma("unroll") for (int mt=0; mt<4; mt++) \
    _Pragma("unroll") for (int nt=0; nt<4; nt++) \
      acc[mt][nt] = __builtin_amdgcn_mfma_f32_16x16x32_f16(A_[mt], B_[nt], acc[mt][nt], 0, 0, 0); }

  LOADA(a0, 0); LOADB(b0, 0);
  #pragma unroll
  for (int ks=0; ks<STEPS; ks+=2){
    LOADA(a1, ks+1); LOADB(b1, ks+1);
    MM(a0, b0);
    if (ks+2 < STEPS){ LOADA(a0, ks+2); LOADB(b0, ks+2); }
    MM(a1, b1);
  }
#undef LOADA
#undef LOADB
#undef MM

  int isb = *flag;
  int s = n0 / 768;
  int h = (n0 % 768) >> 6;
  float bv[4];
  #pragma unroll
  for (int nt=0; nt<4; nt++) bv[nt] = ldf(bias, n0 + nt*16 + mrow, isb);

  #pragma unroll
  for (int mt=0; mt<4; mt++){
    float yv[4][4];   // [nt][r]
    #pragma unroll
    for (int nt=0; nt<4; nt++)
      #pragma unroll
      for (int r=0; r<4; r++)
        yv[nt][r] = leaky(acc[mt][nt][r] + bv[nt]);
    if (s < 2){
      #pragma unroll
      for (int r=0; r<4; r++){
        float ss = yv[0][r]*yv[0][r] + yv[1][r]*yv[1][r]
                 + yv[2][r]*yv[2][r] + yv[3][r]*yv[3][r];
        ss += __shfl_xor(ss, 1); ss += __shfl_xor(ss, 2);
        ss += __shfl_xor(ss, 4); ss += __shfl_xor(ss, 8);
        float rn = 1.f / fmaxf(sqrtf(ss), 1e-8f);
        #pragma unroll
        for (int nt=0; nt<4; nt++) yv[nt][r] *= rn;
      }
    }
    #pragma unroll
    for (int nt=0; nt<4; nt++){
      #pragma unroll
      for (int r=0; r<4; r++){
        int m = m0 + mt*16 + kq*4 + r;
        int dd = nt*16 + mrow;
        int bq = m >> 9, l = m & 511;
        float y = yv[nt][r];
        if (s == 0)      Qh[((size_t)(bq*12 + h)*512 + l)*64 + dd] = (f16)y;
        else if (s == 1) Kh[((size_t)(bq*12 + h)*512 + l)*64 + dd] = (f16)y;
        else             Vt[((size_t)(bq*12 + h)*64 + dd)*512 + l] = (f16)y;
      }
    }
  }
}

// ---------- K3a: scores -> head-LN -> exp (ONCE) -> E (fp16, [b,h,i,j]) + rowsum partials ----------
// grid = b(16) x itile(32) x jtile(16) = 8192 blocks
__global__ __launch_bounds__(256) void k_scores(const f16* __restrict__ Qh,
    const f16* __restrict__ Kh, const void* __restrict__ gamma,
    const void* __restrict__ beta, const int* __restrict__ flag,
    f16* __restrict__ E, float* __restrict__ lsum){
  constexpr int ZS = 402;
  constexpr int TS = 40;
  __shared__ float z[16*ZS];          // [i][h*33 + j]
  __shared__ f16   zt[12*16*TS];      // [h][i][j]
  __shared__ float gL[12], beL[12];

  int tid = threadIdx.x;
  int w = tid >> 6, lane = tid & 63;
  int kq = lane >> 4, mrow = lane & 15;
  int bx = blockIdx.x;
  int jt = bx & 15, it = (bx >> 4) & 31, b = bx >> 9;
  int i0 = it*16, j0 = jt*32;

  if (tid < 12){ int isb = *flag; gL[tid] = ldf(gamma, tid, isb); beL[tid] = ldf(beta, tid, isb); }

  #pragma unroll
  for (int hh=0; hh<3; hh++){
    int h = w*3 + hh;
    const f16* kb = Kh + ((size_t)(b*12+h)*512 + i0 + mrow)*64;
    h8 a0 = *(const h8*)(kb + kq*8);
    h8 a1 = *(const h8*)(kb + 32 + kq*8);
    const f16* qb = Qh + ((size_t)(b*12+h)*512 + j0)*64;
    #pragma unroll
    for (int jn=0; jn<2; jn++){
      const f16* qr = qb + (size_t)(jn*16 + mrow)*64;
      h8 q0 = *(const h8*)(qr + kq*8);
      h8 q1 = *(const h8*)(qr + 32 + kq*8);
      f32x4 c = (f32x4){0.f,0.f,0.f,0.f};
      c = __builtin_amdgcn_mfma_f32_16x16x32_f16(a0, q0, c, 0, 0, 0);
      c = __builtin_amdgcn_mfma_f32_16x16x32_f16(a1, q1, c, 0, 0, 0);
      #pragma unroll
      for (int r=0;r<4;r++)
        z[(kq*4 + r)*ZS + h*33 + jn*16 + mrow] = c[r];
    }
  }
  __syncthreads();
  int pj = tid & 31, piw = tid >> 5;
  #pragma unroll
  for (int p=0; p<2; p++){
    int i = piw + p*8;
    float s[12];
    float mu = 0.f, sq = 0.f;
    #pragma unroll
    for (int h=0;h<12;h++){ s[h] = z[i*ZS + h*33 + pj]; mu += s[h]; sq += s[h]*s[h]; }
    mu *= (1.f/12.f);
    float var = fmaxf(sq*(1.f/12.f) - mu*mu, 0.f);
    float rstd = rsqrtf(var + 1e-5f);
    #pragma unroll
    for (int h=0;h<12;h++){
      float e = __expf((s[h]-mu)*rstd*gL[h] + beL[h]);
      zt[(h*16 + i)*TS + pj] = (f16)e;
    }
  }
  __syncthreads();
  if (tid < 192){
    int h = tid >> 4, i = tid & 15;
    const f16* zr = &zt[(h*16 + i)*TS];
    float ssum = 0.f;
    #pragma unroll
    for (int q=0;q<4;q++){
      h8 v = *(const h8*)(zr + q*8);
      #pragma unroll
      for (int t=0;t<8;t++) ssum += (float)v[t];
    }
    atomicAdd(&lsum[(size_t)(b*12+h)*512 + i0 + i], ssum);
  }
  #pragma unroll
  for (int u0=0; u0<3; u0++){
    int u = tid + u0*256;
    int h = u >> 6, rem = u & 63, i = rem >> 2, q = rem & 3;
    h8 v = *(const h8*)&zt[(h*16 + i)*TS + q*8];
    *(h8*)(E + ((size_t)(b*12+h)*512 + i0 + i)*512 + j0 + q*8) = v;
  }
}

// ---------- K3b: PV MFMA from E, per-(b,h,itile) blocks; colsum via LDS; barrier-free K-loop ----------
// grid = (h*8+it: 96, b: 16) = 1536 blocks, 256 threads; wave = 16i x 64d tile
__global__ __launch_bounds__(256) void k_pv2(const f16* __restrict__ E,
    const f16* __restrict__ Vt, const float* __restrict__ lsum,
    float* __restrict__ O, float* __restrict__ colsum){
  __shared__ float csL[512];
  int tid = threadIdx.x;
  int w = tid >> 6, lane = tid & 63;
  int kq = lane >> 4, mrow = lane & 15;
  int b = blockIdx.y;
  int h = blockIdx.x >> 3, it = blockIdx.x & 7;
  int i0w = it*64 + w*16;

  csL[tid] = 0.f; csL[tid + 256] = 0.f;
  float rinv = 1.f / lsum[(size_t)(b*12+h)*512 + i0w + mrow];
  __syncthreads();

  const f16* erow  = E  + ((size_t)(b*12+h)*512 + i0w + mrow)*512 + kq*8;
  const f16* vbase = Vt + ((size_t)(b*12+h)*64 + mrow)*512 + kq*8;

  f32x4 acc[4];
  #pragma unroll
  for (int nt=0; nt<4; nt++) acc[nt] = (f32x4){0.f,0.f,0.f,0.f};

  #pragma unroll 4
  for (int jt=0; jt<16; jt++){
    int j0 = jt*32;
    h8 ea  = *(const h8*)(erow + j0);
    h8 bf0 = *(const h8*)(vbase + j0);
    h8 bf1 = *(const h8*)(vbase + (size_t)16*512 + j0);
    h8 bf2 = *(const h8*)(vbase + (size_t)32*512 + j0);
    h8 bf3 = *(const h8*)(vbase + (size_t)48*512 + j0);
    acc[0] = __builtin_amdgcn_mfma_f32_16x16x32_f16(ea, bf0, acc[0], 0, 0, 0);
    acc[1] = __builtin_amdgcn_mfma_f32_16x16x32_f16(ea, bf1, acc[1], 0, 0, 0);
    acc[2] = __builtin_amdgcn_mfma_f32_16x16x32_f16(ea, bf2, acc[2], 0, 0, 0);
    acc[3] = __builtin_amdgcn_mfma_f32_16x16x32_f16(ea, bf3, acc[3], 0, 0, 0);
    float cs[8];
    #pragma unroll
    for (int t=0;t<8;t++) cs[t] = (float)ea[t] * rinv;
    #pragma unroll
    for (int t=0;t<8;t++){
      cs[t] += __shfl_xor(cs[t], 1); cs[t] += __shfl_xor(cs[t], 2);
      cs[t] += __shfl_xor(cs[t], 4); cs[t] += __shfl_xor(cs[t], 8);
    }
    if (mrow == 0){
      #pragma unroll
      for (int t=0;t<8;t++) atomicAdd(&csL[j0 + kq*8 + t], cs[t]);
    }
  }
  __syncthreads();
  atomicAdd(&colsum[b*512 + tid],       csL[tid]       * (1.f/12.f));
  atomicAdd(&colsum[b*512 + 256 + tid], csL[tid + 256] * (1.f/12.f));

  // epilogue: O[b, i0w + kq*4+r, h*64 + nt*16 + mrow] = acc[nt][r] / l
  #pragma unroll
  for (int r=0; r<4; r++){
    float g = __shfl(rinv, kq*4 + r);
    #pragma unroll
    for (int nt=0; nt<4; nt++)
      O[((size_t)(b*512) + i0w + kq*4 + r)*768 + h*64 + nt*16 + mrow] = acc[nt][r] * g;
  }
}

// ---------- K3 (fallback, small ws): fused attention, two-sweep ----------
__global__ __launch_bounds__(256) void k_attn2(const f16* __restrict__ Qh,
    const f16* __restrict__ Kh, const f16* __restrict__ Vt,
    const void* __restrict__ gamma, const void* __restrict__ beta,
    const int* __restrict__ flag,
    float* __restrict__ O, float* __restrict__ colsum){
  constexpr int ZS = 421;
  constexpr int TS = 40;
  __shared__ float z[16*ZS];
  __shared__ f16   zt[12*16*TS];
  __shared__ float rsL[192];
  __shared__ float csL[32];
  __shared__ float gL[12], beL[12];

  int tid = threadIdx.x;
  int w = tid >> 6, lane = tid & 63;
  int kq = lane >> 4, mrow = lane & 15;
  int bx = blockIdx.x;
  int b = bx >> 5, i0 = (bx & 31) << 4;
  int pj = tid & 31, pi = tid >> 5;

  if (tid < 12){ int isb = *flag; gL[tid] = ldf(gamma, tid, isb); beL[tid] = ldf(beta, tid, isb); }
  if (tid < 32) csL[tid] = 0.f;

  h8 ak[3][2];
  #pragma unroll
  for (int hh=0; hh<3; hh++){
    int h = w*3 + hh;
    const f16* kb = Kh + ((size_t)(b*12+h)*512 + i0 + mrow)*64;
    #pragma unroll
    for (int ks=0; ks<2; ks++)
      ak[hh][ks] = *(const h8*)(kb + ks*32 + kq*8);
  }
  f32x4 oacc[3][4];
  #pragma unroll
  for (int hh=0; hh<3; hh++)
    #pragma unroll
    for (int nt=0; nt<4; nt++)
      oacc[hh][nt] = (f32x4){0.f,0.f,0.f,0.f};
  float racc[2][12];
  #pragma unroll
  for (int p=0;p<2;p++)
    #pragma unroll
    for (int h=0;h<12;h++) racc[p][h] = 0.f;

  __syncthreads();

  for (int sweep=0; sweep<2; sweep++){
    for (int jt=0; jt<16; jt++){
      #pragma unroll
      for (int hh=0; hh<3; hh++){
        int h = w*3 + hh;
        const f16* qb = Qh + ((size_t)(b*12+h)*512 + jt*32)*64;
        #pragma unroll
        for (int jn=0; jn<2; jn++){
          f32x4 c = (f32x4){0.f,0.f,0.f,0.f};
          #pragma unroll
          for (int ks=0; ks<2; ks++){
            h8 bf = *(const h8*)(qb + (size_t)(jn*16 + mrow)*64 + ks*32 + kq*8);
            c = __builtin_amdgcn_mfma_f32_16x16x32_f16(ak[hh][ks], bf, c, 0, 0, 0);
          }
          int jl = jn*16 + mrow;
          #pragma unroll
          for (int r=0;r<4;r++)
            z[(kq*4 + r)*ZS + jl*13 + h] = c[r];
        }
      }
      __syncthreads();
      #pragma unroll
      for (int p=0; p<2; p++){
        int i = pi + p*8, j = pj;
        const float* zp = &z[i*ZS + j*13];
        float s[12];
        float mu = 0.f, sq = 0.f;
        #pragma unroll
        for (int h=0;h<12;h++){ s[h] = zp[h]; mu += s[h]; sq += s[h]*s[h]; }
        mu *= (1.f/12.f);
        float var = fmaxf(sq*(1.f/12.f) - mu*mu, 0.f);
        float rstd = rsqrtf(var + 1e-5f);
        if (sweep == 0){
          #pragma unroll
          for (int h=0;h<12;h++){
            float e = __expf((s[h]-mu)*rstd*gL[h] + beL[h]);
            racc[p][h] += e;
          }
        } else {
          float cacc = 0.f;
          #pragma unroll
          for (int h=0;h<12;h++){
            float e = __expf((s[h]-mu)*rstd*gL[h] + beL[h]);
            zt[(h*16 + i)*TS + j] = (f16)e;
            cacc += e * rsL[h*16 + i];
          }
          atomicAdd(&csL[j], cacc*(1.f/12.f));
        }
      }
      if (sweep == 0){
        __syncthreads();
      } else {
        __syncthreads();
        #pragma unroll
        for (int hh=0; hh<3; hh++){
          int h = w*3 + hh;
          h8 pa = *(const h8*)&zt[(h*16 + mrow)*TS + kq*8];
          const f16* vb = Vt + ((size_t)(b*12+h)*64)*512;
          #pragma unroll
          for (int nt=0; nt<4; nt++){
            h8 bf = *(const h8*)(vb + (size_t)(nt*16 + mrow)*512 + jt*32 + kq*8);
            oacc[hh][nt] = __builtin_amdgcn_mfma_f32_16x16x32_f16(pa, bf, oacc[hh][nt], 0, 0, 0);
          }
        }
        if (tid < 32){
          atomicAdd(&colsum[b*512 + jt*32 + tid], csL[tid]);
          csL[tid] = 0.f;
        }
      }
    }
    if (sweep == 0){
      #pragma unroll
      for (int p=0;p<2;p++){
        #pragma unroll
        for (int h=0;h<12;h++){
          float v = racc[p][h];
          #pragma unroll
          for (int m=1; m<32; m<<=1) v += __shfl_xor(v, m);
          if ((lane & 31) == 0) rsL[h*16 + (pi + p*8)] = 1.f / v;
        }
      }
      __syncthreads();
    }
  }
  #pragma unroll
  for (int hh=0; hh<3; hh++){
    int h = w*3 + hh;
    #pragma unroll
    for (int nt=0; nt<4; nt++){
      #pragma unroll
      for (int r=0;r<4;r++){
        int i = kq*4 + r;
        float val = oacc[hh][nt][r] * rsL[h*16 + i];
        O[((size_t)(b*512) + i0 + i)*768 + h*64 + nt*16 + mrow] = val;
      }
    }
  }
}

// ---------- K4: probs[m,:] = softmax(O[m,:] @ Wout^T + bout) ----------
__global__ __launch_bounds__(256) void k_probs(const float* __restrict__ O,
    const void* __restrict__ Wout, const void* __restrict__ bout,
    const int* __restrict__ flag, float* __restrict__ probs){
  int isb = *flag;
  int tid = threadIdx.x, wv = tid>>6, lane = tid&63;
  int m = blockIdx.x*4 + wv;
  const float* orow = O + (size_t)m*768;
  float acc[20];
  #pragma unroll
  for (int c=0;c<20;c++) acc[c]=0.f;
  for (int kk=0; kk<12; kk++){
    float o = orow[kk*64 + lane];
    #pragma unroll
    for (int c=0;c<20;c++)
      acc[c] += o * ldf(Wout, c*768 + kk*64 + lane, isb);
  }
  #pragma unroll
  for (int c=0;c<20;c++){
    #pragma unroll
    for (int off=1; off<64; off<<=1) acc[c] += __shfl_xor(acc[c], off, 64);
  }
  float mx = -3.4e38f;
  #pragma unroll
  for (int c=0;c<20;c++){ acc[c] += ldf(bout, c, isb); mx = fmaxf(mx, acc[c]); }
  float s=0.f;
  #pragma unroll
  for (int c=0;c<20;c++){ acc[c] = __expf(acc[c]-mx); s += acc[c]; }
  float inv = 1.f/s;
  if (lane == 0){
    float* pr = probs + (size_t)m*20;
    #pragma unroll
    for (int c=0;c<20;c++) pr[c] = acc[c]*inv;
  }
}

// ---------- K5: weights = softmax(mask*colsum); out[b,:] = sum_l w[l]*probs[b,l,:] ----------
__global__ __launch_bounds__(512) void k_final(const int* __restrict__ ids,
    const float* __restrict__ colsum, const float* __restrict__ probs,
    const int* __restrict__ flag,
    float* __restrict__ accb, void* __restrict__ outp, int br){
  __shared__ float red[8];
  __shared__ float bcast;
  __shared__ float pacc[8][20];
  int b = blockIdx.x, tid = threadIdx.x;
  int wv = tid>>6, lane = tid&63;
  float w = (ids[b*512+tid] != 0) ? colsum[b*512+tid] : 0.f;
  float mx = w;
  #pragma unroll
  for (int off=1; off<64; off<<=1) mx = fmaxf(mx, __shfl_xor(mx, off, 64));
  if (lane==0) red[wv] = mx;
  __syncthreads();
  if (tid==0){ float m2 = red[0]; for (int k2=1;k2<8;k2++) m2 = fmaxf(m2, red[k2]); bcast = m2; }
  __syncthreads();
  float M = bcast;
  float e = __expf(w - M);
  float s = e;
  #pragma unroll
  for (int off=1; off<64; off<<=1) s += __shfl_xor(s, off, 64);
  if (lane==0) red[wv] = s;
  __syncthreads();
  if (tid==0){ float s2=0.f; for (int k2=0;k2<8;k2++) s2 += red[k2]; bcast = s2; }
  __syncthreads();
  float wn = e / bcast;
  float p[20];
  const float* pr = probs + ((size_t)b*512 + tid)*20;
  #pragma unroll
  for (int c=0;c<20;c++) p[c] = wn * pr[c];
  #pragma unroll
  for (int c=0;c<20;c++){
    #pragma unroll
    for (int off=1; off<64; off<<=1) p[c] += __shfl_xor(p[c], off, 64);
  }
  if (lane==0){
    #pragma unroll
    for (int c=0;c<20;c++) pacc[wv][c] = p[c];
  }
  __syncthreads();
  if (tid < 20){
    float s2 = 0.f;
    #pragma unroll
    for (int k2=0;k2<8;k2++) s2 += pacc[k2][tid];
    if (br == 0) accb[b*20 + tid] = s2;
    else {
      float v = (accb[b*20 + tid] + s2) * 0.5f;
      if (*flag) ((ushort*)outp)[b*20 + tid] = f2b(v);
      else       ((float*)outp)[b*20 + tid] = v;
    }
  }
}

extern "C" void kernel_launch(void* const* d_in, const int* in_sizes, int n_in,
                              void* d_out, int out_size, void* d_ws, size_t ws_size,
                              hipStream_t stream){
  (void)in_sizes; (void)n_in; (void)out_size;
  const int*  ids = (const int*)d_in[0];
  const void* wvp = d_in[1];
  const void* emb = d_in[2];
  const void* Wt[2]  = {d_in[3], d_in[9]};
  const void* bt[2]  = {d_in[4], d_in[10]};
  const void* gm[2]  = {d_in[5], d_in[11]};
  const void* bet[2] = {d_in[6], d_in[12]};
  const void* Wo[2]  = {d_in[7], d_in[13]};
  const void* bo[2]  = {d_in[8], d_in[14]};

  float*  O      = (float*)d_ws;            // 6291456 f32
  f16*    Qh     = (f16*)(O + 6291456);     // 6291456 f16
  f16*    Kh     = Qh + 6291456;            // 6291456 f16
  f16*    Vt     = Kh + 6291456;            // 6291456 f16
  f16*    Ah     = Vt + 6291456;            // 6291456 f16
  f16*    Wh     = Ah + 6291456;            // 1769472 f16
  float*  probsb = (float*)(Wh + 1769472);  // 163840 f32
  float*  colsum = probsb + 163840;         // 8192 f32
  float*  accb   = colsum + 8192;           // 320 f32
  int*    flagp  = (int*)(accb + 320);      // 4 ints (pad)
  float*  lsum   = (float*)(flagp + 4);     // 98304 f32
  f16*    E      = (f16*)(lsum + 98304);    // 50331648 f16 (100.7 MB, optional)
  size_t  need   = (size_t)((char*)(E + 50331648) - (char*)d_ws);
  int bigws = (ws_size >= need);

  k_detect<<<1, 64, 0, stream>>>((const ushort*)wvp, flagp);

  for (int br=0; br<2; br++){
    if (br==0){
      k_build_x<<<3072, 256, 0, stream>>>(ids, emb, Ah, flagp);
      k_prep<<<864, 256, 0, stream>>>(Wt[0], Wh, 768, 96, flagp);
    } else {
      k_prep<<<1280, 256, 0, stream>>>(wvp, Ah, 300, 40, flagp);
      k_prep<<<360, 256, 0, stream>>>(Wt[1], Wh, 300, 40, flagp);
    }
    k_zero<<<416, 256, 0, stream>>>(colsum, lsum);
    dim3 g1(128, 9);
    if (br==0) k_gemm_mfma<768><<<g1, 256, 0, stream>>>(Ah, Wh, bt[0], flagp, Qh, Kh, Vt);
    else       k_gemm_mfma<320><<<g1, 256, 0, stream>>>(Ah, Wh, bt[1], flagp, Qh, Kh, Vt);
    if (bigws){
      k_scores<<<8192, 256, 0, stream>>>(Qh, Kh, gm[br], bet[br], flagp, E, lsum);
      dim3 gpv(96, 16);
      k_pv2<<<gpv, 256, 0, stream>>>(E, Vt, lsum, O, colsum);
    } else {
      k_attn2<<<512, 256, 0, stream>>>(Qh, Kh, Vt, gm[br], bet[br], flagp, O, colsum);
    }
    k_probs<<<2048, 256, 0, stream>>>(O, Wo[br], bo[br], flagp, probsb);
    k_final<<<16, 512, 0, stream>>>(ids, colsum, probsb, flagp, accb, d_out, br);
  }
}

// Round 7
// 652.096 us; speedup vs baseline: 1.7626x; 1.1377x over previous
//
#include <hip/hip_runtime.h>

typedef unsigned int uint;
typedef unsigned short ushort;
typedef _Float16 f16;
typedef _Float16 h8 __attribute__((ext_vector_type(8)));
typedef float f32x4 __attribute__((ext_vector_type(4)));

// B=16 L=512 H=12 d=64 D=768 N3=2304 C=20 M=8192

__device__ __forceinline__ float b2f(ushort u){ return __uint_as_float(((uint)u)<<16); }
__device__ __forceinline__ ushort f2b(float f){
  uint u = __float_as_uint(f);
  uint r = u + 0x7fffu + ((u>>16)&1u);
  return (ushort)(r>>16);
}
__device__ __forceinline__ float leaky(float x){ return x >= 0.f ? x : 0.01f*x; }
__device__ __forceinline__ float ldf(const void* p, int idx, int isb){
  return isb ? b2f(((const ushort*)p)[idx]) : ((const float*)p)[idx];
}

#define GLOAD16(gp, lp) __builtin_amdgcn_global_load_lds( \
    (const __attribute__((address_space(1))) void*)(gp), \
    (__attribute__((address_space(3))) void*)(lp), 16, 0, 0)

// ---------- K-1: detect whether float tensors arrived as bf16 (1) or f32 (0) ----------
__global__ void k_detect(const ushort* __restrict__ wvbits, int* __restrict__ flag){
  if (blockIdx.x==0 && threadIdx.x==0){
    int sane = 0;
    for (int i=0;i<128;i++){
      uint e = (wvbits[i]>>7)&0xffu;
      if (e==0u || (e>=90u && e<=150u)) sane++;
    }
    *flag = (sane >= 115) ? 1 : 0;
  }
}

// ---------- K-0: zero colsum (32x256) and lsum (384x256) ----------
__global__ __launch_bounds__(256) void k_zero(float* __restrict__ colsum,
    float* __restrict__ lsum){
  int bid = blockIdx.x, tid = threadIdx.x;
  if (bid < 32) colsum[bid*256 + tid] = 0.f;
  else          lsum[(bid-32)*256 + tid] = 0.f;
}

// ---------- K0: Ah[m,k] = leaky(emb[ids[m],k])  (fp16 out, KP=768) ----------
__global__ __launch_bounds__(256) void k_build_x(const int* __restrict__ ids,
    const void* __restrict__ emb, f16* __restrict__ Ah, const int* __restrict__ flag){
  int isb = *flag;
  int t = blockIdx.x*256 + threadIdx.x;
  int m = t / 96;
  int kk = (t % 96) * 8;
  float o[8];
  if (isb){
    const ushort* src = (const ushort*)emb + (size_t)ids[m]*768 + kk;
    uint4 v = *(const uint4*)src;
    o[0]=__uint_as_float((v.x&0xffffu)<<16); o[1]=__uint_as_float(v.x&0xffff0000u);
    o[2]=__uint_as_float((v.y&0xffffu)<<16); o[3]=__uint_as_float(v.y&0xffff0000u);
    o[4]=__uint_as_float((v.z&0xffffu)<<16); o[5]=__uint_as_float(v.z&0xffff0000u);
    o[6]=__uint_as_float((v.w&0xffffu)<<16); o[7]=__uint_as_float(v.w&0xffff0000u);
  } else {
    const float* src = (const float*)emb + (size_t)ids[m]*768 + kk;
    float4 v0 = ((const float4*)src)[0];
    float4 v1 = ((const float4*)src)[1];
    o[0]=v0.x; o[1]=v0.y; o[2]=v0.z; o[3]=v0.w;
    o[4]=v1.x; o[5]=v1.y; o[6]=v1.z; o[7]=v1.w;
  }
  h8 hv;
  #pragma unroll
  for (int i=0;i<8;i++) hv[i] = (f16)leaky(o[i]);
  *(h8*)(Ah + (size_t)m*768 + kk) = hv;
}

// ---------- K0b: generic fp16 repack with zero-pad: dst[n,KP] from src[n,Ksrc] ----------
__global__ __launch_bounds__(256) void k_prep(const void* __restrict__ src,
    f16* __restrict__ dst, int Ksrc, int kp8, const int* __restrict__ flag){
  int isb = *flag;
  int t = blockIdx.x*256 + threadIdx.x;
  int n = t / kp8;
  int kk = (t % kp8) * 8;
  h8 hv;
  #pragma unroll
  for (int i=0;i<8;i++){
    int k = kk + i;
    hv[i] = (k < Ksrc) ? (f16)ldf(src, n*Ksrc + k, isb) : (f16)0.f;
  }
  *(h8*)(dst + (size_t)n*(kp8*8) + kk) = hv;
}

// ---------- K1: MFMA QKV GEMM, m97-style LDS staging + fused Q/K row-normalize ----------
// 128x128 tile, BK=64, global_load_lds width=16, XOR chunk swizzle (slot q holds
// global chunk q^(row&7)): staging stays lane-contiguous, frag reads 2-way max.
// 4 waves/block, each wave a 64x64 subtile (4x4 frags of 16x16x32).
template<int KP>
__global__ __launch_bounds__(256) void k_gemm_mfma(const f16* __restrict__ Ah,
    const f16* __restrict__ Wh, const void* __restrict__ bias, const int* __restrict__ flag,
    f16* __restrict__ Qh, f16* __restrict__ Kh, f16* __restrict__ Vt){
  constexpr int STEPS = KP/64;
  __shared__ __align__(16) f16 As[128*64];
  __shared__ __align__(16) f16 Bs[128*64];
  int tid = threadIdx.x;
  int w = tid >> 6, lane = tid & 63;
  int mrow = lane & 15, kq = lane >> 4;
  int m0 = blockIdx.x * 128;
  int n0 = blockIdx.y * 128;
  int msub = (w & 1) * 64, nsub = (w >> 1) * 64;

  f32x4 acc[4][4];
  #pragma unroll
  for (int mt=0; mt<4; mt++)
    #pragma unroll
    for (int nt=0; nt<4; nt++) acc[mt][nt] = (f32x4){0.f,0.f,0.f,0.f};

  // staging chunk geometry (per rep): chunk c = rep*256 + w*64 + lane
  int cbase = w*64 + lane;

  for (int step=0; step<STEPS; step++){
    int k0 = step*64;
    __syncthreads();
    #pragma unroll
    for (int rep=0; rep<4; rep++){
      int cb = rep*256 + w*64;          // wave-uniform LDS chunk base
      int c  = rep*256 + cbase;         // this lane's chunk
      int row = c >> 3;
      int qs  = (c & 7) ^ (row & 7);
      GLOAD16(Ah + (size_t)(m0+row)*KP + k0 + qs*8, As + cb*8);
      GLOAD16(Wh + (size_t)(n0+row)*KP + k0 + qs*8, Bs + cb*8);
    }
    __syncthreads();
    #pragma unroll
    for (int ks=0; ks<2; ks++){
      h8 af[4], bf[4];
      #pragma unroll
      for (int mt=0; mt<4; mt++){
        int row = msub + mt*16 + mrow;
        int slot = (ks*4 + kq) ^ (row & 7);
        af[mt] = *(const h8*)(As + row*64 + slot*8);
      }
      #pragma unroll
      for (int nt=0; nt<4; nt++){
        int row = nsub + nt*16 + mrow;
        int slot = (ks*4 + kq) ^ (row & 7);
        bf[nt] = *(const h8*)(Bs + row*64 + slot*8);
      }
      #pragma unroll
      for (int mt=0; mt<4; mt++)
        #pragma unroll
        for (int nt=0; nt<4; nt++)
          acc[mt][nt] = __builtin_amdgcn_mfma_f32_16x16x32_f16(af[mt], bf[nt], acc[mt][nt], 0, 0, 0);
    }
  }

  int isb = *flag;
  int n0w = n0 + nsub;
  int s = n0w / 768;
  int h = (n0w % 768) >> 6;
  float bv[4];
  #pragma unroll
  for (int nt=0; nt<4; nt++) bv[nt] = ldf(bias, n0w + nt*16 + mrow, isb);

  #pragma unroll
  for (int mt=0; mt<4; mt++){
    float yv[4][4];   // [nt][r]
    #pragma unroll
    for (int nt=0; nt<4; nt++)
      #pragma unroll
      for (int r=0; r<4; r++)
        yv[nt][r] = leaky(acc[mt][nt][r] + bv[nt]);
    if (s < 2){
      #pragma unroll
      for (int r=0; r<4; r++){
        float ss = yv[0][r]*yv[0][r] + yv[1][r]*yv[1][r]
                 + yv[2][r]*yv[2][r] + yv[3][r]*yv[3][r];
        ss += __shfl_xor(ss, 1); ss += __shfl_xor(ss, 2);
        ss += __shfl_xor(ss, 4); ss += __shfl_xor(ss, 8);
        float rn = 1.f / fmaxf(sqrtf(ss), 1e-8f);
        #pragma unroll
        for (int nt=0; nt<4; nt++) yv[nt][r] *= rn;
      }
    }
    #pragma unroll
    for (int nt=0; nt<4; nt++){
      #pragma unroll
      for (int r=0; r<4; r++){
        int m = m0 + msub + mt*16 + kq*4 + r;
        int dd = nt*16 + mrow;
        int bq = m >> 9, l = m & 511;
        float y = yv[nt][r];
        if (s == 0)      Qh[((size_t)(bq*12 + h)*512 + l)*64 + dd] = (f16)y;
        else if (s == 1) Kh[((size_t)(bq*12 + h)*512 + l)*64 + dd] = (f16)y;
        else             Vt[((size_t)(bq*12 + h)*64 + dd)*512 + l] = (f16)y;
      }
    }
  }
}

// ---------- K3a: scores -> head-LN -> exp (ONCE) -> E (fp16, [b,h,i,j]) + rowsum partials ----------
// grid = b(16) x itile(32) x jtile(16) = 8192 blocks
__global__ __launch_bounds__(256) void k_scores(const f16* __restrict__ Qh,
    const f16* __restrict__ Kh, const void* __restrict__ gamma,
    const void* __restrict__ beta, const int* __restrict__ flag,
    f16* __restrict__ E, float* __restrict__ lsum){
  constexpr int ZS = 402;
  constexpr int TS = 40;
  __shared__ float z[16*ZS];          // [i][h*33 + j]
  __shared__ f16   zt[12*16*TS];      // [h][i][j]
  __shared__ float gL[12], beL[12];

  int tid = threadIdx.x;
  int w = tid >> 6, lane = tid & 63;
  int kq = lane >> 4, mrow = lane & 15;
  int bx = blockIdx.x;
  int jt = bx & 15, it = (bx >> 4) & 31, b = bx >> 9;
  int i0 = it*16, j0 = jt*32;

  if (tid < 12){ int isb = *flag; gL[tid] = ldf(gamma, tid, isb); beL[tid] = ldf(beta, tid, isb); }

  #pragma unroll
  for (int hh=0; hh<3; hh++){
    int h = w*3 + hh;
    const f16* kb = Kh + ((size_t)(b*12+h)*512 + i0 + mrow)*64;
    h8 a0 = *(const h8*)(kb + kq*8);
    h8 a1 = *(const h8*)(kb + 32 + kq*8);
    const f16* qb = Qh + ((size_t)(b*12+h)*512 + j0)*64;
    #pragma unroll
    for (int jn=0; jn<2; jn++){
      const f16* qr = qb + (size_t)(jn*16 + mrow)*64;
      h8 q0 = *(const h8*)(qr + kq*8);
      h8 q1 = *(const h8*)(qr + 32 + kq*8);
      f32x4 c = (f32x4){0.f,0.f,0.f,0.f};
      c = __builtin_amdgcn_mfma_f32_16x16x32_f16(a0, q0, c, 0, 0, 0);
      c = __builtin_amdgcn_mfma_f32_16x16x32_f16(a1, q1, c, 0, 0, 0);
      #pragma unroll
      for (int r=0;r<4;r++)
        z[(kq*4 + r)*ZS + h*33 + jn*16 + mrow] = c[r];
    }
  }
  __syncthreads();
  int pj = tid & 31, piw = tid >> 5;
  #pragma unroll
  for (int p=0; p<2; p++){
    int i = piw + p*8;
    float s[12];
    float mu = 0.f, sq = 0.f;
    #pragma unroll
    for (int h=0;h<12;h++){ s[h] = z[i*ZS + h*33 + pj]; mu += s[h]; sq += s[h]*s[h]; }
    mu *= (1.f/12.f);
    float var = fmaxf(sq*(1.f/12.f) - mu*mu, 0.f);
    float rstd = rsqrtf(var + 1e-5f);
    #pragma unroll
    for (int h=0;h<12;h++){
      float e = __expf((s[h]-mu)*rstd*gL[h] + beL[h]);
      zt[(h*16 + i)*TS + pj] = (f16)e;
    }
  }
  __syncthreads();
  if (tid < 192){
    int h = tid >> 4, i = tid & 15;
    const f16* zr = &zt[(h*16 + i)*TS];
    float ssum = 0.f;
    #pragma unroll
    for (int q=0;q<4;q++){
      h8 v = *(const h8*)(zr + q*8);
      #pragma unroll
      for (int t=0;t<8;t++) ssum += (float)v[t];
    }
    atomicAdd(&lsum[(size_t)(b*12+h)*512 + i0 + i], ssum);
  }
  #pragma unroll
  for (int u0=0; u0<3; u0++){
    int u = tid + u0*256;
    int h = u >> 6, rem = u & 63, i = rem >> 2, q = rem & 3;
    h8 v = *(const h8*)&zt[(h*16 + i)*TS + q*8];
    *(h8*)(E + ((size_t)(b*12+h)*512 + i0 + i)*512 + j0 + q*8) = v;
  }
}

// ---------- K3b: PV MFMA from E, per-(b,h,itile) blocks; colsum via LDS; barrier-free K-loop ----------
// grid = (h*8+it: 96, b: 16) = 1536 blocks, 256 threads; wave = 16i x 64d tile
__global__ __launch_bounds__(256) void k_pv2(const f16* __restrict__ E,
    const f16* __restrict__ Vt, const float* __restrict__ lsum,
    float* __restrict__ O, float* __restrict__ colsum){
  __shared__ float csL[512];
  int tid = threadIdx.x;
  int w = tid >> 6, lane = tid & 63;
  int kq = lane >> 4, mrow = lane & 15;
  int b = blockIdx.y;
  int h = blockIdx.x >> 3, it = blockIdx.x & 7;
  int i0w = it*64 + w*16;

  csL[tid] = 0.f; csL[tid + 256] = 0.f;
  float rinv = 1.f / lsum[(size_t)(b*12+h)*512 + i0w + mrow];
  __syncthreads();

  const f16* erow  = E  + ((size_t)(b*12+h)*512 + i0w + mrow)*512 + kq*8;
  const f16* vbase = Vt + ((size_t)(b*12+h)*64 + mrow)*512 + kq*8;

  f32x4 acc[4];
  #pragma unroll
  for (int nt=0; nt<4; nt++) acc[nt] = (f32x4){0.f,0.f,0.f,0.f};

  #pragma unroll 4
  for (int jt=0; jt<16; jt++){
    int j0 = jt*32;
    h8 ea  = *(const h8*)(erow + j0);
    h8 bf0 = *(const h8*)(vbase + j0);
    h8 bf1 = *(const h8*)(vbase + (size_t)16*512 + j0);
    h8 bf2 = *(const h8*)(vbase + (size_t)32*512 + j0);
    h8 bf3 = *(const h8*)(vbase + (size_t)48*512 + j0);
    acc[0] = __builtin_amdgcn_mfma_f32_16x16x32_f16(ea, bf0, acc[0], 0, 0, 0);
    acc[1] = __builtin_amdgcn_mfma_f32_16x16x32_f16(ea, bf1, acc[1], 0, 0, 0);
    acc[2] = __builtin_amdgcn_mfma_f32_16x16x32_f16(ea, bf2, acc[2], 0, 0, 0);
    acc[3] = __builtin_amdgcn_mfma_f32_16x16x32_f16(ea, bf3, acc[3], 0, 0, 0);
    float cs[8];
    #pragma unroll
    for (int t=0;t<8;t++) cs[t] = (float)ea[t] * rinv;
    #pragma unroll
    for (int t=0;t<8;t++){
      cs[t] += __shfl_xor(cs[t], 1); cs[t] += __shfl_xor(cs[t], 2);
      cs[t] += __shfl_xor(cs[t], 4); cs[t] += __shfl_xor(cs[t], 8);
    }
    if (mrow == 0){
      #pragma unroll
      for (int t=0;t<8;t++) atomicAdd(&csL[j0 + kq*8 + t], cs[t]);
    }
  }
  __syncthreads();
  atomicAdd(&colsum[b*512 + tid],       csL[tid]       * (1.f/12.f));
  atomicAdd(&colsum[b*512 + 256 + tid], csL[tid + 256] * (1.f/12.f));

  #pragma unroll
  for (int r=0; r<4; r++){
    float g = __shfl(rinv, kq*4 + r);
    #pragma unroll
    for (int nt=0; nt<4; nt++)
      O[((size_t)(b*512) + i0w + kq*4 + r)*768 + h*64 + nt*16 + mrow] = acc[nt][r] * g;
  }
}

// ---------- K3 (fallback, small ws): fused attention, two-sweep ----------
__global__ __launch_bounds__(256) void k_attn2(const f16* __restrict__ Qh,
    const f16* __restrict__ Kh, const f16* __restrict__ Vt,
    const void* __restrict__ gamma, const void* __restrict__ beta,
    const int* __restrict__ flag,
    float* __restrict__ O, float* __restrict__ colsum){
  constexpr int ZS = 421;
  constexpr int TS = 40;
  __shared__ float z[16*ZS];
  __shared__ f16   zt[12*16*TS];
  __shared__ float rsL[192];
  __shared__ float csL[32];
  __shared__ float gL[12], beL[12];

  int tid = threadIdx.x;
  int w = tid >> 6, lane = tid & 63;
  int kq = lane >> 4, mrow = lane & 15;
  int bx = blockIdx.x;
  int b = bx >> 5, i0 = (bx & 31) << 4;
  int pj = tid & 31, pi = tid >> 5;

  if (tid < 12){ int isb = *flag; gL[tid] = ldf(gamma, tid, isb); beL[tid] = ldf(beta, tid, isb); }
  if (tid < 32) csL[tid] = 0.f;

  h8 ak[3][2];
  #pragma unroll
  for (int hh=0; hh<3; hh++){
    int h = w*3 + hh;
    const f16* kb = Kh + ((size_t)(b*12+h)*512 + i0 + mrow)*64;
    #pragma unroll
    for (int ks=0; ks<2; ks++)
      ak[hh][ks] = *(const h8*)(kb + ks*32 + kq*8);
  }
  f32x4 oacc[3][4];
  #pragma unroll
  for (int hh=0; hh<3; hh++)
    #pragma unroll
    for (int nt=0; nt<4; nt++)
      oacc[hh][nt] = (f32x4){0.f,0.f,0.f,0.f};
  float racc[2][12];
  #pragma unroll
  for (int p=0;p<2;p++)
    #pragma unroll
    for (int h=0;h<12;h++) racc[p][h] = 0.f;

  __syncthreads();

  for (int sweep=0; sweep<2; sweep++){
    for (int jt=0; jt<16; jt++){
      #pragma unroll
      for (int hh=0; hh<3; hh++){
        int h = w*3 + hh;
        const f16* qb = Qh + ((size_t)(b*12+h)*512 + jt*32)*64;
        #pragma unroll
        for (int jn=0; jn<2; jn++){
          f32x4 c = (f32x4){0.f,0.f,0.f,0.f};
          #pragma unroll
          for (int ks=0; ks<2; ks++){
            h8 bf = *(const h8*)(qb + (size_t)(jn*16 + mrow)*64 + ks*32 + kq*8);
            c = __builtin_amdgcn_mfma_f32_16x16x32_f16(ak[hh][ks], bf, c, 0, 0, 0);
          }
          int jl = jn*16 + mrow;
          #pragma unroll
          for (int r=0;r<4;r++)
            z[(kq*4 + r)*ZS + jl*13 + h] = c[r];
        }
      }
      __syncthreads();
      #pragma unroll
      for (int p=0; p<2; p++){
        int i = pi + p*8, j = pj;
        const float* zp = &z[i*ZS + j*13];
        float s[12];
        float mu = 0.f, sq = 0.f;
        #pragma unroll
        for (int h=0;h<12;h++){ s[h] = zp[h]; mu += s[h]; sq += s[h]*s[h]; }
        mu *= (1.f/12.f);
        float var = fmaxf(sq*(1.f/12.f) - mu*mu, 0.f);
        float rstd = rsqrtf(var + 1e-5f);
        if (sweep == 0){
          #pragma unroll
          for (int h=0;h<12;h++){
            float e = __expf((s[h]-mu)*rstd*gL[h] + beL[h]);
            racc[p][h] += e;
          }
        } else {
          float cacc = 0.f;
          #pragma unroll
          for (int h=0;h<12;h++){
            float e = __expf((s[h]-mu)*rstd*gL[h] + beL[h]);
            zt[(h*16 + i)*TS + j] = (f16)e;
            cacc += e * rsL[h*16 + i];
          }
          atomicAdd(&csL[j], cacc*(1.f/12.f));
        }
      }
      if (sweep == 0){
        __syncthreads();
      } else {
        __syncthreads();
        #pragma unroll
        for (int hh=0; hh<3; hh++){
          int h = w*3 + hh;
          h8 pa = *(const h8*)&zt[(h*16 + mrow)*TS + kq*8];
          const f16* vb = Vt + ((size_t)(b*12+h)*64)*512;
          #pragma unroll
          for (int nt=0; nt<4; nt++){
            h8 bf = *(const h8*)(vb + (size_t)(nt*16 + mrow)*512 + jt*32 + kq*8);
            oacc[hh][nt] = __builtin_amdgcn_mfma_f32_16x16x32_f16(pa, bf, oacc[hh][nt], 0, 0, 0);
          }
        }
        if (tid < 32){
          atomicAdd(&colsum[b*512 + jt*32 + tid], csL[tid]);
          csL[tid] = 0.f;
        }
      }
    }
    if (sweep == 0){
      #pragma unroll
      for (int p=0;p<2;p++){
        #pragma unroll
        for (int h=0;h<12;h++){
          float v = racc[p][h];
          #pragma unroll
          for (int m=1; m<32; m<<=1) v += __shfl_xor(v, m);
          if ((lane & 31) == 0) rsL[h*16 + (pi + p*8)] = 1.f / v;
        }
      }
      __syncthreads();
    }
  }
  #pragma unroll
  for (int hh=0; hh<3; hh++){
    int h = w*3 + hh;
    #pragma unroll
    for (int nt=0; nt<4; nt++){
      #pragma unroll
      for (int r=0;r<4;r++){
        int i = kq*4 + r;
        float val = oacc[hh][nt][r] * rsL[h*16 + i];
        O[((size_t)(b*512) + i0 + i)*768 + h*64 + nt*16 + mrow] = val;
      }
    }
  }
}

// ---------- K4: probs[m,:] = softmax(O[m,:] @ Wout^T + bout) ----------
__global__ __launch_bounds__(256) void k_probs(const float* __restrict__ O,
    const void* __restrict__ Wout, const void* __restrict__ bout,
    const int* __restrict__ flag, float* __restrict__ probs){
  int isb = *flag;
  int tid = threadIdx.x, wv = tid>>6, lane = tid&63;
  int m = blockIdx.x*4 + wv;
  const float* orow = O + (size_t)m*768;
  float acc[20];
  #pragma unroll
  for (int c=0;c<20;c++) acc[c]=0.f;
  for (int kk=0; kk<12; kk++){
    float o = orow[kk*64 + lane];
    #pragma unroll
    for (int c=0;c<20;c++)
      acc[c] += o * ldf(Wout, c*768 + kk*64 + lane, isb);
  }
  #pragma unroll
  for (int c=0;c<20;c++){
    #pragma unroll
    for (int off=1; off<64; off<<=1) acc[c] += __shfl_xor(acc[c], off, 64);
  }
  float mx = -3.4e38f;
  #pragma unroll
  for (int c=0;c<20;c++){ acc[c] += ldf(bout, c, isb); mx = fmaxf(mx, acc[c]); }
  float s=0.f;
  #pragma unroll
  for (int c=0;c<20;c++){ acc[c] = __expf(acc[c]-mx); s += acc[c]; }
  float inv = 1.f/s;
  if (lane == 0){
    float* pr = probs + (size_t)m*20;
    #pragma unroll
    for (int c=0;c<20;c++) pr[c] = acc[c]*inv;
  }
}

// ---------- K5: weights = softmax(mask*colsum); out[b,:] = sum_l w[l]*probs[b,l,:] ----------
__global__ __launch_bounds__(512) void k_final(const int* __restrict__ ids,
    const float* __restrict__ colsum, const float* __restrict__ probs,
    const int* __restrict__ flag,
    float* __restrict__ accb, void* __restrict__ outp, int br){
  __shared__ float red[8];
  __shared__ float bcast;
  __shared__ float pacc[8][20];
  int b = blockIdx.x, tid = threadIdx.x;
  int wv = tid>>6, lane = tid&63;
  float w = (ids[b*512+tid] != 0) ? colsum[b*512+tid] : 0.f;
  float mx = w;
  #pragma unroll
  for (int off=1; off<64; off<<=1) mx = fmaxf(mx, __shfl_xor(mx, off, 64));
  if (lane==0) red[wv] = mx;
  __syncthreads();
  if (tid==0){ float m2 = red[0]; for (int k2=1;k2<8;k2++) m2 = fmaxf(m2, red[k2]); bcast = m2; }
  __syncthreads();
  float M = bcast;
  float e = __expf(w - M);
  float s = e;
  #pragma unroll
  for (int off=1; off<64; off<<=1) s += __shfl_xor(s, off, 64);
  if (lane==0) red[wv] = s;
  __syncthreads();
  if (tid==0){ float s2=0.f; for (int k2=0;k2<8;k2++) s2 += red[k2]; bcast = s2; }
  __syncthreads();
  float wn = e / bcast;
  float p[20];
  const float* pr = probs + ((size_t)b*512 + tid)*20;
  #pragma unroll
  for (int c=0;c<20;c++) p[c] = wn * pr[c];
  #pragma unroll
  for (int c=0;c<20;c++){
    #pragma unroll
    for (int off=1; off<64; off<<=1) p[c] += __shfl_xor(p[c], off, 64);
  }
  if (lane==0){
    #pragma unroll
    for (int c=0;c<20;c++) pacc[wv][c] = p[c];
  }
  __syncthreads();
  if (tid < 20){
    float s2 = 0.f;
    #pragma unroll
    for (int k2=0;k2<8;k2++) s2 += pacc[k2][tid];
    if (br == 0) accb[b*20 + tid] = s2;
    else {
      float v = (accb[b*20 + tid] + s2) * 0.5f;
      if (*flag) ((ushort*)outp)[b*20 + tid] = f2b(v);
      else       ((float*)outp)[b*20 + tid] = v;
    }
  }
}

extern "C" void kernel_launch(void* const* d_in, const int* in_sizes, int n_in,
                              void* d_out, int out_size, void* d_ws, size_t ws_size,
                              hipStream_t stream){
  (void)in_sizes; (void)n_in; (void)out_size;
  const int*  ids = (const int*)d_in[0];
  const void* wvp = d_in[1];
  const void* emb = d_in[2];
  const void* Wt[2]  = {d_in[3], d_in[9]};
  const void* bt[2]  = {d_in[4], d_in[10]};
  const void* gm[2]  = {d_in[5], d_in[11]};
  const void* bet[2] = {d_in[6], d_in[12]};
  const void* Wo[2]  = {d_in[7], d_in[13]};
  const void* bo[2]  = {d_in[8], d_in[14]};

  float*  O      = (float*)d_ws;            // 6291456 f32
  f16*    Qh     = (f16*)(O + 6291456);     // 6291456 f16
  f16*    Kh     = Qh + 6291456;            // 6291456 f16
  f16*    Vt     = Kh + 6291456;            // 6291456 f16
  f16*    Ah     = Vt + 6291456;            // 6291456 f16
  f16*    Wh     = Ah + 6291456;            // 1769472 f16
  float*  probsb = (float*)(Wh + 1769472);  // 163840 f32
  float*  colsum = probsb + 163840;         // 8192 f32
  float*  accb   = colsum + 8192;           // 320 f32
  int*    flagp  = (int*)(accb + 320);      // 4 ints (pad)
  float*  lsum   = (float*)(flagp + 4);     // 98304 f32
  f16*    E      = (f16*)(lsum + 98304);    // 50331648 f16 (100.7 MB, optional)
  size_t  need   = (size_t)((char*)(E + 50331648) - (char*)d_ws);
  int bigws = (ws_size >= need);

  k_detect<<<1, 64, 0, stream>>>((const ushort*)wvp, flagp);

  for (int br=0; br<2; br++){
    if (br==0){
      k_build_x<<<3072, 256, 0, stream>>>(ids, emb, Ah, flagp);
      k_prep<<<864, 256, 0, stream>>>(Wt[0], Wh, 768, 96, flagp);
    } else {
      k_prep<<<1280, 256, 0, stream>>>(wvp, Ah, 300, 40, flagp);
      k_prep<<<360, 256, 0, stream>>>(Wt[1], Wh, 300, 40, flagp);
    }
    k_zero<<<416, 256, 0, stream>>>(colsum, lsum);
    dim3 g1(64, 18);
    if (br==0) k_gemm_mfma<768><<<g1, 256, 0, stream>>>(Ah, Wh, bt[0], flagp, Qh, Kh, Vt);
    else       k_gemm_mfma<320><<<g1, 256, 0, stream>>>(Ah, Wh, bt[1], flagp, Qh, Kh, Vt);
    if (bigws){
      k_scores<<<8192, 256, 0, stream>>>(Qh, Kh, gm[br], bet[br], flagp, E, lsum);
      dim3 gpv(96, 16);
      k_pv2<<<gpv, 256, 0, stream>>>(E, Vt, lsum, O, colsum);
    } else {
      k_attn2<<<512, 256, 0, stream>>>(Qh, Kh, Vt, gm[br], bet[br], flagp, O, colsum);
    }
    k_probs<<<2048, 256, 0, stream>>>(O, Wo[br], bo[br], flagp, probsb);
    k_final<<<16, 512, 0, stream>>>(ids, colsum, probsb, flagp, accb, d_out, br);
  }
}

// Round 8
// 622.323 us; speedup vs baseline: 1.8469x; 1.0478x over previous
//
#include <hip/hip_runtime.h>

typedef unsigned int uint;
typedef unsigned short ushort;
typedef _Float16 f16;
typedef _Float16 h8 __attribute__((ext_vector_type(8)));
typedef float f32x4 __attribute__((ext_vector_type(4)));

// B=16 L=512 H=12 d=64 D=768 N3=2304 C=20 M=8192

__device__ __forceinline__ float b2f(ushort u){ return __uint_as_float(((uint)u)<<16); }
__device__ __forceinline__ ushort f2b(float f){
  uint u = __float_as_uint(f);
  uint r = u + 0x7fffu + ((u>>16)&1u);
  return (ushort)(r>>16);
}
__device__ __forceinline__ float leaky(float x){ return x >= 0.f ? x : 0.01f*x; }
__device__ __forceinline__ float ldf(const void* p, int idx, int isb){
  return isb ? b2f(((const ushort*)p)[idx]) : ((const float*)p)[idx];
}

#define GLOAD16(gp, lp) __builtin_amdgcn_global_load_lds( \
    (const __attribute__((address_space(1))) void*)(gp), \
    (__attribute__((address_space(3))) void*)(lp), 16, 0, 0)

// ---------- K-1: detect whether float tensors arrived as bf16 (1) or f32 (0) ----------
__global__ void k_detect(const ushort* __restrict__ wvbits, int* __restrict__ flag){
  if (blockIdx.x==0 && threadIdx.x==0){
    int sane = 0;
    for (int i=0;i<128;i++){
      uint e = (wvbits[i]>>7)&0xffu;
      if (e==0u || (e>=90u && e<=150u)) sane++;
    }
    *flag = (sane >= 115) ? 1 : 0;
  }
}

// ---------- K-0: zero colsum (32x256) and lsum (384x256) ----------
__global__ __launch_bounds__(256) void k_zero(float* __restrict__ colsum,
    float* __restrict__ lsum){
  int bid = blockIdx.x, tid = threadIdx.x;
  if (bid < 32) colsum[bid*256 + tid] = 0.f;
  else          lsum[(bid-32)*256 + tid] = 0.f;
}

// ---------- K0: Ah[m,k] = leaky(emb[ids[m],k])  (fp16 out, KP=768) ----------
__global__ __launch_bounds__(256) void k_build_x(const int* __restrict__ ids,
    const void* __restrict__ emb, f16* __restrict__ Ah, const int* __restrict__ flag){
  int isb = *flag;
  int t = blockIdx.x*256 + threadIdx.x;
  int m = t / 96;
  int kk = (t % 96) * 8;
  float o[8];
  if (isb){
    const ushort* src = (const ushort*)emb + (size_t)ids[m]*768 + kk;
    uint4 v = *(const uint4*)src;
    o[0]=__uint_as_float((v.x&0xffffu)<<16); o[1]=__uint_as_float(v.x&0xffff0000u);
    o[2]=__uint_as_float((v.y&0xffffu)<<16); o[3]=__uint_as_float(v.y&0xffff0000u);
    o[4]=__uint_as_float((v.z&0xffffu)<<16); o[5]=__uint_as_float(v.z&0xffff0000u);
    o[6]=__uint_as_float((v.w&0xffffu)<<16); o[7]=__uint_as_float(v.w&0xffff0000u);
  } else {
    const float* src = (const float*)emb + (size_t)ids[m]*768 + kk;
    float4 v0 = ((const float4*)src)[0];
    float4 v1 = ((const float4*)src)[1];
    o[0]=v0.x; o[1]=v0.y; o[2]=v0.z; o[3]=v0.w;
    o[4]=v1.x; o[5]=v1.y; o[6]=v1.z; o[7]=v1.w;
  }
  h8 hv;
  #pragma unroll
  for (int i=0;i<8;i++) hv[i] = (f16)leaky(o[i]);
  *(h8*)(Ah + (size_t)m*768 + kk) = hv;
}

// ---------- K0b: generic fp16 repack with zero-pad: dst[n,KP] from src[n,Ksrc] ----------
__global__ __launch_bounds__(256) void k_prep(const void* __restrict__ src,
    f16* __restrict__ dst, int Ksrc, int kp8, const int* __restrict__ flag){
  int isb = *flag;
  int t = blockIdx.x*256 + threadIdx.x;
  int n = t / kp8;
  int kk = (t % kp8) * 8;
  h8 hv;
  #pragma unroll
  for (int i=0;i<8;i++){
    int k = kk + i;
    hv[i] = (k < Ksrc) ? (f16)ldf(src, n*Ksrc + k, isb) : (f16)0.f;
  }
  *(h8*)(dst + (size_t)n*(kp8*8) + kk) = hv;
}

// ---------- K1: MFMA QKV GEMM, m97-style LDS staging + fused Q/K row-normalize ----------
template<int KP>
__global__ __launch_bounds__(256) void k_gemm_mfma(const f16* __restrict__ Ah,
    const f16* __restrict__ Wh, const void* __restrict__ bias, const int* __restrict__ flag,
    f16* __restrict__ Qh, f16* __restrict__ Kh, f16* __restrict__ Vt){
  constexpr int STEPS = KP/64;
  __shared__ __align__(16) f16 As[128*64];
  __shared__ __align__(16) f16 Bs[128*64];
  int tid = threadIdx.x;
  int w = tid >> 6, lane = tid & 63;
  int mrow = lane & 15, kq = lane >> 4;
  int m0 = blockIdx.x * 128;
  int n0 = blockIdx.y * 128;
  int msub = (w & 1) * 64, nsub = (w >> 1) * 64;

  f32x4 acc[4][4];
  #pragma unroll
  for (int mt=0; mt<4; mt++)
    #pragma unroll
    for (int nt=0; nt<4; nt++) acc[mt][nt] = (f32x4){0.f,0.f,0.f,0.f};

  int cbase = w*64 + lane;

  for (int step=0; step<STEPS; step++){
    int k0 = step*64;
    __syncthreads();
    #pragma unroll
    for (int rep=0; rep<4; rep++){
      int cb = rep*256 + w*64;
      int c  = rep*256 + cbase;
      int row = c >> 3;
      int qs  = (c & 7) ^ (row & 7);
      GLOAD16(Ah + (size_t)(m0+row)*KP + k0 + qs*8, As + cb*8);
      GLOAD16(Wh + (size_t)(n0+row)*KP + k0 + qs*8, Bs + cb*8);
    }
    __syncthreads();
    #pragma unroll
    for (int ks=0; ks<2; ks++){
      h8 af[4], bf[4];
      #pragma unroll
      for (int mt=0; mt<4; mt++){
        int row = msub + mt*16 + mrow;
        int slot = (ks*4 + kq) ^ (row & 7);
        af[mt] = *(const h8*)(As + row*64 + slot*8);
      }
      #pragma unroll
      for (int nt=0; nt<4; nt++){
        int row = nsub + nt*16 + mrow;
        int slot = (ks*4 + kq) ^ (row & 7);
        bf[nt] = *(const h8*)(Bs + row*64 + slot*8);
      }
      #pragma unroll
      for (int mt=0; mt<4; mt++)
        #pragma unroll
        for (int nt=0; nt<4; nt++)
          acc[mt][nt] = __builtin_amdgcn_mfma_f32_16x16x32_f16(af[mt], bf[nt], acc[mt][nt], 0, 0, 0);
    }
  }

  int isb = *flag;
  int n0w = n0 + nsub;
  int s = n0w / 768;
  int h = (n0w % 768) >> 6;
  float bv[4];
  #pragma unroll
  for (int nt=0; nt<4; nt++) bv[nt] = ldf(bias, n0w + nt*16 + mrow, isb);

  #pragma unroll
  for (int mt=0; mt<4; mt++){
    float yv[4][4];
    #pragma unroll
    for (int nt=0; nt<4; nt++)
      #pragma unroll
      for (int r=0; r<4; r++)
        yv[nt][r] = leaky(acc[mt][nt][r] + bv[nt]);
    if (s < 2){
      #pragma unroll
      for (int r=0; r<4; r++){
        float ss = yv[0][r]*yv[0][r] + yv[1][r]*yv[1][r]
                 + yv[2][r]*yv[2][r] + yv[3][r]*yv[3][r];
        ss += __shfl_xor(ss, 1); ss += __shfl_xor(ss, 2);
        ss += __shfl_xor(ss, 4); ss += __shfl_xor(ss, 8);
        float rn = 1.f / fmaxf(sqrtf(ss), 1e-8f);
        #pragma unroll
        for (int nt=0; nt<4; nt++) yv[nt][r] *= rn;
      }
    }
    #pragma unroll
    for (int nt=0; nt<4; nt++){
      #pragma unroll
      for (int r=0; r<4; r++){
        int m = m0 + msub + mt*16 + kq*4 + r;
        int dd = nt*16 + mrow;
        int bq = m >> 9, l = m & 511;
        float y = yv[nt][r];
        if (s == 0)      Qh[((size_t)(bq*12 + h)*512 + l)*64 + dd] = (f16)y;
        else if (s == 1) Kh[((size_t)(bq*12 + h)*512 + l)*64 + dd] = (f16)y;
        else             Vt[((size_t)(bq*12 + h)*64 + dd)*512 + l] = (f16)y;
      }
    }
  }
}

// ---------- K3a: scores -> head-LN -> exp -> E (fp16, [b,h,i,j]) + rowsum partials ----------
// 64-wide j tiles: full 128B-line E writes. Single f16 LDS buffer S[h][i][j], LN in place.
// grid = b(16) x itile(32) x jtile(8) = 4096 blocks
__global__ __launch_bounds__(256) void k_scores(const f16* __restrict__ Qh,
    const f16* __restrict__ Kh, const void* __restrict__ gamma,
    const void* __restrict__ beta, const int* __restrict__ flag,
    f16* __restrict__ E, float* __restrict__ lsum){
  constexpr int TS = 72;              // halves per (h,i) row (64 j + 8 pad, 16B aligned)
  __shared__ f16 S[12*16*TS];         // 27.6 KB
  __shared__ float gL[12], beL[12];

  int tid = threadIdx.x;
  int w = tid >> 6, lane = tid & 63;
  int kq = lane >> 4, mrow = lane & 15;
  int bx = blockIdx.x;
  int jt = bx & 7, it = (bx >> 3) & 31, b = bx >> 8;
  int i0 = it*16, j0 = jt*64;

  if (tid < 12){ int isb = *flag; gL[tid] = ldf(gamma, tid, isb); beL[tid] = ldf(beta, tid, isb); }

  // QK^T: 16i x 64j for this wave's 3 heads; C scattered as f16 into S
  #pragma unroll
  for (int hh=0; hh<3; hh++){
    int h = w*3 + hh;
    const f16* kb = Kh + ((size_t)(b*12+h)*512 + i0 + mrow)*64;
    h8 a0 = *(const h8*)(kb + kq*8);
    h8 a1 = *(const h8*)(kb + 32 + kq*8);
    const f16* qb = Qh + ((size_t)(b*12+h)*512 + j0)*64;
    #pragma unroll
    for (int jn=0; jn<4; jn++){
      const f16* qr = qb + (size_t)(jn*16 + mrow)*64;
      h8 q0 = *(const h8*)(qr + kq*8);
      h8 q1 = *(const h8*)(qr + 32 + kq*8);
      f32x4 c = (f32x4){0.f,0.f,0.f,0.f};
      c = __builtin_amdgcn_mfma_f32_16x16x32_f16(a0, q0, c, 0, 0, 0);
      c = __builtin_amdgcn_mfma_f32_16x16x32_f16(a1, q1, c, 0, 0, 0);
      #pragma unroll
      for (int r=0;r<4;r++)
        S[(h*16 + kq*4 + r)*TS + jn*16 + mrow] = (f16)c[r];
    }
  }
  __syncthreads();
  // LN over heads + exp, in place (each column owned by one thread)
  int pj = tid & 63, piw = tid >> 6;
  #pragma unroll
  for (int p=0; p<4; p++){
    int i = piw*4 + p;
    float s[12];
    float mu = 0.f, sq = 0.f;
    #pragma unroll
    for (int h=0;h<12;h++){ s[h] = (float)S[(h*16+i)*TS + pj]; mu += s[h]; sq += s[h]*s[h]; }
    mu *= (1.f/12.f);
    float var = fmaxf(sq*(1.f/12.f) - mu*mu, 0.f);
    float rstd = rsqrtf(var + 1e-5f);
    #pragma unroll
    for (int h=0;h<12;h++){
      float e = __expf((s[h]-mu)*rstd*gL[h] + beL[h]);
      S[(h*16+i)*TS + pj] = (f16)e;
    }
  }
  __syncthreads();
  // rowsum partials: thread t<192 sums its (h,i) row over 64 j
  if (tid < 192){
    int h = tid >> 4, i = tid & 15;
    const f16* zr = &S[(h*16 + i)*TS];
    float ssum = 0.f;
    #pragma unroll
    for (int q=0;q<8;q++){
      h8 v = *(const h8*)(zr + q*8);
      #pragma unroll
      for (int t=0;t<8;t++) ssum += (float)v[t];
    }
    atomicAdd(&lsum[(size_t)(b*12+h)*512 + i0 + i], ssum);
  }
  // E copy-out: 1536 h8-units, 6 per thread; 8 consecutive lanes = one 128B line
  #pragma unroll
  for (int u0=0; u0<6; u0++){
    int u = tid + u0*256;
    int h = u >> 7, rem = u & 127, i = rem >> 3, q = rem & 7;
    h8 v = *(const h8*)&S[(h*16 + i)*TS + q*8];
    *(h8*)(E + ((size_t)(b*12+h)*512 + i0 + i)*512 + j0 + q*8) = v;
  }
}

// ---------- K3b: PV MFMA from E, per-(b,h,itile) blocks; colsum via LDS; barrier-free K-loop ----------
// grid = (h*8+it: 96, b: 16) = 1536 blocks, 256 threads; wave = 16i x 64d tile
__global__ __launch_bounds__(256) void k_pv2(const f16* __restrict__ E,
    const f16* __restrict__ Vt, const float* __restrict__ lsum,
    float* __restrict__ O, float* __restrict__ colsum){
  __shared__ float csL[512];
  int tid = threadIdx.x;
  int w = tid >> 6, lane = tid & 63;
  int kq = lane >> 4, mrow = lane & 15;
  int b = blockIdx.y;
  int h = blockIdx.x >> 3, it = blockIdx.x & 7;
  int i0w = it*64 + w*16;

  csL[tid] = 0.f; csL[tid + 256] = 0.f;
  float rinv = 1.f / lsum[(size_t)(b*12+h)*512 + i0w + mrow];
  __syncthreads();

  const f16* erow  = E  + ((size_t)(b*12+h)*512 + i0w + mrow)*512 + kq*8;
  const f16* vbase = Vt + ((size_t)(b*12+h)*64 + mrow)*512 + kq*8;

  f32x4 acc[4];
  #pragma unroll
  for (int nt=0; nt<4; nt++) acc[nt] = (f32x4){0.f,0.f,0.f,0.f};

  #pragma unroll 4
  for (int jt=0; jt<16; jt++){
    int j0 = jt*32;
    h8 ea  = *(const h8*)(erow + j0);
    h8 bf0 = *(const h8*)(vbase + j0);
    h8 bf1 = *(const h8*)(vbase + (size_t)16*512 + j0);
    h8 bf2 = *(const h8*)(vbase + (size_t)32*512 + j0);
    h8 bf3 = *(const h8*)(vbase + (size_t)48*512 + j0);
    acc[0] = __builtin_amdgcn_mfma_f32_16x16x32_f16(ea, bf0, acc[0], 0, 0, 0);
    acc[1] = __builtin_amdgcn_mfma_f32_16x16x32_f16(ea, bf1, acc[1], 0, 0, 0);
    acc[2] = __builtin_amdgcn_mfma_f32_16x16x32_f16(ea, bf2, acc[2], 0, 0, 0);
    acc[3] = __builtin_amdgcn_mfma_f32_16x16x32_f16(ea, bf3, acc[3], 0, 0, 0);
    float cs[8];
    #pragma unroll
    for (int t=0;t<8;t++) cs[t] = (float)ea[t] * rinv;
    #pragma unroll
    for (int t=0;t<8;t++){
      cs[t] += __shfl_xor(cs[t], 1); cs[t] += __shfl_xor(cs[t], 2);
      cs[t] += __shfl_xor(cs[t], 4); cs[t] += __shfl_xor(cs[t], 8);
    }
    if (mrow == 0){
      #pragma unroll
      for (int t=0;t<8;t++) atomicAdd(&csL[j0 + kq*8 + t], cs[t]);
    }
  }
  __syncthreads();
  atomicAdd(&colsum[b*512 + tid],       csL[tid]       * (1.f/12.f));
  atomicAdd(&colsum[b*512 + 256 + tid], csL[tid + 256] * (1.f/12.f));

  #pragma unroll
  for (int r=0; r<4; r++){
    float g = __shfl(rinv, kq*4 + r);
    #pragma unroll
    for (int nt=0; nt<4; nt++)
      O[((size_t)(b*512) + i0w + kq*4 + r)*768 + h*64 + nt*16 + mrow] = acc[nt][r] * g;
  }
}

// ---------- K3 (fallback, small ws): fused attention, two-sweep ----------
__global__ __launch_bounds__(256) void k_attn2(const f16* __restrict__ Qh,
    const f16* __restrict__ Kh, const f16* __restrict__ Vt,
    const void* __restrict__ gamma, const void* __restrict__ beta,
    const int* __restrict__ flag,
    float* __restrict__ O, float* __restrict__ colsum){
  constexpr int ZS = 421;
  constexpr int TS = 40;
  __shared__ float z[16*ZS];
  __shared__ f16   zt[12*16*TS];
  __shared__ float rsL[192];
  __shared__ float csL[32];
  __shared__ float gL[12], beL[12];

  int tid = threadIdx.x;
  int w = tid >> 6, lane = tid & 63;
  int kq = lane >> 4, mrow = lane & 15;
  int bx = blockIdx.x;
  int b = bx >> 5, i0 = (bx & 31) << 4;
  int pj = tid & 31, pi = tid >> 5;

  if (tid < 12){ int isb = *flag; gL[tid] = ldf(gamma, tid, isb); beL[tid] = ldf(beta, tid, isb); }
  if (tid < 32) csL[tid] = 0.f;

  h8 ak[3][2];
  #pragma unroll
  for (int hh=0; hh<3; hh++){
    int h = w*3 + hh;
    const f16* kb = Kh + ((size_t)(b*12+h)*512 + i0 + mrow)*64;
    #pragma unroll
    for (int ks=0; ks<2; ks++)
      ak[hh][ks] = *(const h8*)(kb + ks*32 + kq*8);
  }
  f32x4 oacc[3][4];
  #pragma unroll
  for (int hh=0; hh<3; hh++)
    #pragma unroll
    for (int nt=0; nt<4; nt++)
      oacc[hh][nt] = (f32x4){0.f,0.f,0.f,0.f};
  float racc[2][12];
  #pragma unroll
  for (int p=0;p<2;p++)
    #pragma unroll
    for (int h=0;h<12;h++) racc[p][h] = 0.f;

  __syncthreads();

  for (int sweep=0; sweep<2; sweep++){
    for (int jt=0; jt<16; jt++){
      #pragma unroll
      for (int hh=0; hh<3; hh++){
        int h = w*3 + hh;
        const f16* qb = Qh + ((size_t)(b*12+h)*512 + jt*32)*64;
        #pragma unroll
        for (int jn=0; jn<2; jn++){
          f32x4 c = (f32x4){0.f,0.f,0.f,0.f};
          #pragma unroll
          for (int ks=0; ks<2; ks++){
            h8 bf = *(const h8*)(qb + (size_t)(jn*16 + mrow)*64 + ks*32 + kq*8);
            c = __builtin_amdgcn_mfma_f32_16x16x32_f16(ak[hh][ks], bf, c, 0, 0, 0);
          }
          int jl = jn*16 + mrow;
          #pragma unroll
          for (int r=0;r<4;r++)
            z[(kq*4 + r)*ZS + jl*13 + h] = c[r];
        }
      }
      __syncthreads();
      #pragma unroll
      for (int p=0; p<2; p++){
        int i = pi + p*8, j = pj;
        const float* zp = &z[i*ZS + j*13];
        float s[12];
        float mu = 0.f, sq = 0.f;
        #pragma unroll
        for (int h=0;h<12;h++){ s[h] = zp[h]; mu += s[h]; sq += s[h]*s[h]; }
        mu *= (1.f/12.f);
        float var = fmaxf(sq*(1.f/12.f) - mu*mu, 0.f);
        float rstd = rsqrtf(var + 1e-5f);
        if (sweep == 0){
          #pragma unroll
          for (int h=0;h<12;h++){
            float e = __expf((s[h]-mu)*rstd*gL[h] + beL[h]);
            racc[p][h] += e;
          }
        } else {
          float cacc = 0.f;
          #pragma unroll
          for (int h=0;h<12;h++){
            float e = __expf((s[h]-mu)*rstd*gL[h] + beL[h]);
            zt[(h*16 + i)*TS + j] = (f16)e;
            cacc += e * rsL[h*16 + i];
          }
          atomicAdd(&csL[j], cacc*(1.f/12.f));
        }
      }
      if (sweep == 0){
        __syncthreads();
      } else {
        __syncthreads();
        #pragma unroll
        for (int hh=0; hh<3; hh++){
          int h = w*3 + hh;
          h8 pa = *(const h8*)&zt[(h*16 + mrow)*TS + kq*8];
          const f16* vb = Vt + ((size_t)(b*12+h)*64)*512;
          #pragma unroll
          for (int nt=0; nt<4; nt++){
            h8 bf = *(const h8*)(vb + (size_t)(nt*16 + mrow)*512 + jt*32 + kq*8);
            oacc[hh][nt] = __builtin_amdgcn_mfma_f32_16x16x32_f16(pa, bf, oacc[hh][nt], 0, 0, 0);
          }
        }
        if (tid < 32){
          atomicAdd(&colsum[b*512 + jt*32 + tid], csL[tid]);
          csL[tid] = 0.f;
        }
      }
    }
    if (sweep == 0){
      #pragma unroll
      for (int p=0;p<2;p++){
        #pragma unroll
        for (int h=0;h<12;h++){
          float v = racc[p][h];
          #pragma unroll
          for (int m=1; m<32; m<<=1) v += __shfl_xor(v, m);
          if ((lane & 31) == 0) rsL[h*16 + (pi + p*8)] = 1.f / v;
        }
      }
      __syncthreads();
    }
  }
  #pragma unroll
  for (int hh=0; hh<3; hh++){
    int h = w*3 + hh;
    #pragma unroll
    for (int nt=0; nt<4; nt++){
      #pragma unroll
      for (int r=0;r<4;r++){
        int i = kq*4 + r;
        float val = oacc[hh][nt][r] * rsL[h*16 + i];
        O[((size_t)(b*512) + i0 + i)*768 + h*64 + nt*16 + mrow] = val;
      }
    }
  }
}

// ---------- K4: probs[m,:] = softmax(O[m,:] @ Wout^T + bout) ----------
__global__ __launch_bounds__(256) void k_probs(const float* __restrict__ O,
    const void* __restrict__ Wout, const void* __restrict__ bout,
    const int* __restrict__ flag, float* __restrict__ probs){
  int isb = *flag;
  int tid = threadIdx.x, wv = tid>>6, lane = tid&63;
  int m = blockIdx.x*4 + wv;
  const float* orow = O + (size_t)m*768;
  float acc[20];
  #pragma unroll
  for (int c=0;c<20;c++) acc[c]=0.f;
  for (int kk=0; kk<12; kk++){
    float o = orow[kk*64 + lane];
    #pragma unroll
    for (int c=0;c<20;c++)
      acc[c] += o * ldf(Wout, c*768 + kk*64 + lane, isb);
  }
  #pragma unroll
  for (int c=0;c<20;c++){
    #pragma unroll
    for (int off=1; off<64; off<<=1) acc[c] += __shfl_xor(acc[c], off, 64);
  }
  float mx = -3.4e38f;
  #pragma unroll
  for (int c=0;c<20;c++){ acc[c] += ldf(bout, c, isb); mx = fmaxf(mx, acc[c]); }
  float s=0.f;
  #pragma unroll
  for (int c=0;c<20;c++){ acc[c] = __expf(acc[c]-mx); s += acc[c]; }
  float inv = 1.f/s;
  if (lane == 0){
    float* pr = probs + (size_t)m*20;
    #pragma unroll
    for (int c=0;c<20;c++) pr[c] = acc[c]*inv;
  }
}

// ---------- K5: weights = softmax(mask*colsum); out[b,:] = sum_l w[l]*probs[b,l,:] ----------
__global__ __launch_bounds__(512) void k_final(const int* __restrict__ ids,
    const float* __restrict__ colsum, const float* __restrict__ probs,
    const int* __restrict__ flag,
    float* __restrict__ accb, void* __restrict__ outp, int br){
  __shared__ float red[8];
  __shared__ float bcast;
  __shared__ float pacc[8][20];
  int b = blockIdx.x, tid = threadIdx.x;
  int wv = tid>>6, lane = tid&63;
  float w = (ids[b*512+tid] != 0) ? colsum[b*512+tid] : 0.f;
  float mx = w;
  #pragma unroll
  for (int off=1; off<64; off<<=1) mx = fmaxf(mx, __shfl_xor(mx, off, 64));
  if (lane==0) red[wv] = mx;
  __syncthreads();
  if (tid==0){ float m2 = red[0]; for (int k2=1;k2<8;k2++) m2 = fmaxf(m2, red[k2]); bcast = m2; }
  __syncthreads();
  float M = bcast;
  float e = __expf(w - M);
  float s = e;
  #pragma unroll
  for (int off=1; off<64; off<<=1) s += __shfl_xor(s, off, 64);
  if (lane==0) red[wv] = s;
  __syncthreads();
  if (tid==0){ float s2=0.f; for (int k2=0;k2<8;k2++) s2 += red[k2]; bcast = s2; }
  __syncthreads();
  float wn = e / bcast;
  float p[20];
  const float* pr = probs + ((size_t)b*512 + tid)*20;
  #pragma unroll
  for (int c=0;c<20;c++) p[c] = wn * pr[c];
  #pragma unroll
  for (int c=0;c<20;c++){
    #pragma unroll
    for (int off=1; off<64; off<<=1) p[c] += __shfl_xor(p[c], off, 64);
  }
  if (lane==0){
    #pragma unroll
    for (int c=0;c<20;c++) pacc[wv][c] = p[c];
  }
  __syncthreads();
  if (tid < 20){
    float s2 = 0.f;
    #pragma unroll
    for (int k2=0;k2<8;k2++) s2 += pacc[k2][tid];
    if (br == 0) accb[b*20 + tid] = s2;
    else {
      float v = (accb[b*20 + tid] + s2) * 0.5f;
      if (*flag) ((ushort*)outp)[b*20 + tid] = f2b(v);
      else       ((float*)outp)[b*20 + tid] = v;
    }
  }
}

extern "C" void kernel_launch(void* const* d_in, const int* in_sizes, int n_in,
                              void* d_out, int out_size, void* d_ws, size_t ws_size,
                              hipStream_t stream){
  (void)in_sizes; (void)n_in; (void)out_size;
  const int*  ids = (const int*)d_in[0];
  const void* wvp = d_in[1];
  const void* emb = d_in[2];
  const void* Wt[2]  = {d_in[3], d_in[9]};
  const void* bt[2]  = {d_in[4], d_in[10]};
  const void* gm[2]  = {d_in[5], d_in[11]};
  const void* bet[2] = {d_in[6], d_in[12]};
  const void* Wo[2]  = {d_in[7], d_in[13]};
  const void* bo[2]  = {d_in[8], d_in[14]};

  float*  O      = (float*)d_ws;            // 6291456 f32
  f16*    Qh     = (f16*)(O + 6291456);     // 6291456 f16
  f16*    Kh     = Qh + 6291456;            // 6291456 f16
  f16*    Vt     = Kh + 6291456;            // 6291456 f16
  f16*    Ah     = Vt + 6291456;            // 6291456 f16
  f16*    Wh     = Ah + 6291456;            // 1769472 f16
  float*  probsb = (float*)(Wh + 1769472);  // 163840 f32
  float*  colsum = probsb + 163840;         // 8192 f32
  float*  accb   = colsum + 8192;           // 320 f32
  int*    flagp  = (int*)(accb + 320);      // 4 ints (pad)
  float*  lsum   = (float*)(flagp + 4);     // 98304 f32
  f16*    E      = (f16*)(lsum + 98304);    // 50331648 f16 (100.7 MB, optional)
  size_t  need   = (size_t)((char*)(E + 50331648) - (char*)d_ws);
  int bigws = (ws_size >= need);

  k_detect<<<1, 64, 0, stream>>>((const ushort*)wvp, flagp);

  for (int br=0; br<2; br++){
    if (br==0){
      k_build_x<<<3072, 256, 0, stream>>>(ids, emb, Ah, flagp);
      k_prep<<<864, 256, 0, stream>>>(Wt[0], Wh, 768, 96, flagp);
    } else {
      k_prep<<<1280, 256, 0, stream>>>(wvp, Ah, 300, 40, flagp);
      k_prep<<<360, 256, 0, stream>>>(Wt[1], Wh, 300, 40, flagp);
    }
    k_zero<<<416, 256, 0, stream>>>(colsum, lsum);
    dim3 g1(64, 18);
    if (br==0) k_gemm_mfma<768><<<g1, 256, 0, stream>>>(Ah, Wh, bt[0], flagp, Qh, Kh, Vt);
    else       k_gemm_mfma<320><<<g1, 256, 0, stream>>>(Ah, Wh, bt[1], flagp, Qh, Kh, Vt);
    if (bigws){
      k_scores<<<4096, 256, 0, stream>>>(Qh, Kh, gm[br], bet[br], flagp, E, lsum);
      dim3 gpv(96, 16);
      k_pv2<<<gpv, 256, 0, stream>>>(E, Vt, lsum, O, colsum);
    } else {
      k_attn2<<<512, 256, 0, stream>>>(Qh, Kh, Vt, gm[br], bet[br], flagp, O, colsum);
    }
    k_probs<<<2048, 256, 0, stream>>>(O, Wo[br], bo[br], flagp, probsb);
    k_final<<<16, 512, 0, stream>>>(ids, colsum, probsb, flagp, accb, d_out, br);
  }
}

// Round 9
// 577.917 us; speedup vs baseline: 1.9888x; 1.0768x over previous
//
#include <hip/hip_runtime.h>

typedef unsigned int uint;
typedef unsigned short ushort;
typedef _Float16 f16;
typedef _Float16 h8 __attribute__((ext_vector_type(8)));
typedef float f32x4 __attribute__((ext_vector_type(4)));

// B=16 L=512 H=12 d=64 D=768 N3=2304 C=20 M=8192

__device__ __forceinline__ float b2f(ushort u){ return __uint_as_float(((uint)u)<<16); }
__device__ __forceinline__ ushort f2b(float f){
  uint u = __float_as_uint(f);
  uint r = u + 0x7fffu + ((u>>16)&1u);
  return (ushort)(r>>16);
}
__device__ __forceinline__ float leaky(float x){ return x >= 0.f ? x : 0.01f*x; }
__device__ __forceinline__ float ldf(const void* p, int idx, int isb){
  return isb ? b2f(((const ushort*)p)[idx]) : ((const float*)p)[idx];
}

#define GLOAD16(gp, lp) __builtin_amdgcn_global_load_lds( \
    (const __attribute__((address_space(1))) void*)(gp), \
    (__attribute__((address_space(3))) void*)(lp), 16, 0, 0)

// ---------- K_init: detect dtype (block 0) + zero colsum0/1+lsum0/1 (blocks 1..832) ----------
__global__ __launch_bounds__(256) void k_init(const ushort* __restrict__ wvbits,
    int* __restrict__ flag, float* __restrict__ zbase){
  int bid = blockIdx.x, tid = threadIdx.x;
  if (bid == 0){
    if (tid == 0){
      int sane = 0;
      for (int i=0;i<128;i++){
        uint e = (wvbits[i]>>7)&0xffu;
        if (e==0u || (e>=90u && e<=150u)) sane++;
      }
      *flag = (sane >= 115) ? 1 : 0;
    }
  } else {
    zbase[(bid-1)*256 + tid] = 0.f;   // 832*256 = 212992 floats
  }
}

// ---------- K_prep_all: build_x + up to 3 repacks, range-dispatched on blockIdx.x ----------
// jobs: [0,nBX) leaky(emb[ids]) -> AhA (768); [.., +nW0) W0 768 -> WhA;
//       [.., +nA1) wv 300->320 -> AhB;        [.., +nW1) W1 300->320 -> WhB
__global__ __launch_bounds__(256) void k_prep_all(const int* __restrict__ ids,
    const void* __restrict__ emb, const void* __restrict__ wv,
    const void* __restrict__ W0, const void* __restrict__ W1,
    const int* __restrict__ flag,
    f16* __restrict__ AhA, f16* __restrict__ WhA,
    f16* __restrict__ AhB, f16* __restrict__ WhB,
    int nBX, int nW0, int nA1, int nW1){
  int isb = *flag;
  int bx = blockIdx.x, tid = threadIdx.x;
  if (bx < nBX){
    int t = bx*256 + tid;            // 8192*96 units
    int m = t / 96, kk = (t % 96) * 8;
    float o[8];
    if (isb){
      const ushort* src = (const ushort*)emb + (size_t)ids[m]*768 + kk;
      uint4 v = *(const uint4*)src;
      o[0]=__uint_as_float((v.x&0xffffu)<<16); o[1]=__uint_as_float(v.x&0xffff0000u);
      o[2]=__uint_as_float((v.y&0xffffu)<<16); o[3]=__uint_as_float(v.y&0xffff0000u);
      o[4]=__uint_as_float((v.z&0xffffu)<<16); o[5]=__uint_as_float(v.z&0xffff0000u);
      o[6]=__uint_as_float((v.w&0xffffu)<<16); o[7]=__uint_as_float(v.w&0xffff0000u);
    } else {
      const float* src = (const float*)emb + (size_t)ids[m]*768 + kk;
      float4 v0 = ((const float4*)src)[0];
      float4 v1 = ((const float4*)src)[1];
      o[0]=v0.x; o[1]=v0.y; o[2]=v0.z; o[3]=v0.w;
      o[4]=v1.x; o[5]=v1.y; o[6]=v1.z; o[7]=v1.w;
    }
    h8 hv;
    #pragma unroll
    for (int i=0;i<8;i++) hv[i] = (f16)leaky(o[i]);
    *(h8*)(AhA + (size_t)m*768 + kk) = hv;
  } else if (bx < nBX + nW0){
    int t = (bx - nBX)*256 + tid;    // 2304*96 units
    int n = t / 96, kk = (t % 96) * 8;
    h8 hv;
    #pragma unroll
    for (int i=0;i<8;i++) hv[i] = (f16)ldf(W0, n*768 + kk + i, isb);
    *(h8*)(WhA + (size_t)n*768 + kk) = hv;
  } else if (bx < nBX + nW0 + nA1){
    int t = (bx - nBX - nW0)*256 + tid;  // 8192*40 units
    int n = t / 40, kk = (t % 40) * 8;
    h8 hv;
    #pragma unroll
    for (int i=0;i<8;i++){
      int k = kk + i;
      hv[i] = (k < 300) ? (f16)ldf(wv, n*300 + k, isb) : (f16)0.f;
    }
    *(h8*)(AhB + (size_t)n*320 + kk) = hv;
  } else {
    int t = (bx - nBX - nW0 - nA1)*256 + tid;  // 2304*40 units
    int n = t / 40, kk = (t % 40) * 8;
    h8 hv;
    #pragma unroll
    for (int i=0;i<8;i++){
      int k = kk + i;
      hv[i] = (k < 300) ? (f16)ldf(W1, n*300 + k, isb) : (f16)0.f;
    }
    *(h8*)(WhB + (size_t)n*320 + kk) = hv;
  }
}

// ---------- K1: merged MFMA QKV GEMM (branch by blockIdx.z), m97 LDS staging, fused QK-norm ----------
__global__ __launch_bounds__(256) void k_gemm_m(
    const f16* AhA, const f16* WhA, const void* biasA, int KA,
    f16* QhA, f16* KhA, f16* VtA,
    const f16* AhB, const f16* WhB, const void* biasB, int KB,
    f16* QhB, f16* KhB, f16* VtB,
    const int* __restrict__ flag, int sbase){
  __shared__ __align__(16) f16 As[128*64];
  __shared__ __align__(16) f16 Bs[128*64];
  int z = sbase + blockIdx.z;
  const f16* Ah = z ? AhB : AhA;
  const f16* Wh = z ? WhB : WhA;
  const void* bias = z ? biasB : biasA;
  int KP = z ? KB : KA;
  f16* Qh = z ? QhB : QhA;
  f16* Kh = z ? KhB : KhA;
  f16* Vt = z ? VtB : VtA;
  int STEPS = KP >> 6;

  int tid = threadIdx.x;
  int w = tid >> 6, lane = tid & 63;
  int mrow = lane & 15, kq = lane >> 4;
  int m0 = blockIdx.x * 128;
  int n0 = blockIdx.y * 128;
  int msub = (w & 1) * 64, nsub = (w >> 1) * 64;

  f32x4 acc[4][4];
  #pragma unroll
  for (int mt=0; mt<4; mt++)
    #pragma unroll
    for (int nt=0; nt<4; nt++) acc[mt][nt] = (f32x4){0.f,0.f,0.f,0.f};

  int cbase = w*64 + lane;

  for (int step=0; step<STEPS; step++){
    int k0 = step*64;
    __syncthreads();
    #pragma unroll
    for (int rep=0; rep<4; rep++){
      int cb = rep*256 + w*64;
      int c  = rep*256 + cbase;
      int row = c >> 3;
      int qs  = (c & 7) ^ (row & 7);
      GLOAD16(Ah + (size_t)(m0+row)*KP + k0 + qs*8, As + cb*8);
      GLOAD16(Wh + (size_t)(n0+row)*KP + k0 + qs*8, Bs + cb*8);
    }
    __syncthreads();
    #pragma unroll
    for (int ks=0; ks<2; ks++){
      h8 af[4], bf[4];
      #pragma unroll
      for (int mt=0; mt<4; mt++){
        int row = msub + mt*16 + mrow;
        int slot = (ks*4 + kq) ^ (row & 7);
        af[mt] = *(const h8*)(As + row*64 + slot*8);
      }
      #pragma unroll
      for (int nt=0; nt<4; nt++){
        int row = nsub + nt*16 + mrow;
        int slot = (ks*4 + kq) ^ (row & 7);
        bf[nt] = *(const h8*)(Bs + row*64 + slot*8);
      }
      #pragma unroll
      for (int mt=0; mt<4; mt++)
        #pragma unroll
        for (int nt=0; nt<4; nt++)
          acc[mt][nt] = __builtin_amdgcn_mfma_f32_16x16x32_f16(af[mt], bf[nt], acc[mt][nt], 0, 0, 0);
    }
  }

  int isb = *flag;
  int n0w = n0 + nsub;
  int s = n0w / 768;
  int h = (n0w % 768) >> 6;
  float bv[4];
  #pragma unroll
  for (int nt=0; nt<4; nt++) bv[nt] = ldf(bias, n0w + nt*16 + mrow, isb);

  #pragma unroll
  for (int mt=0; mt<4; mt++){
    float yv[4][4];
    #pragma unroll
    for (int nt=0; nt<4; nt++)
      #pragma unroll
      for (int r=0; r<4; r++)
        yv[nt][r] = leaky(acc[mt][nt][r] + bv[nt]);
    if (s < 2){
      #pragma unroll
      for (int r=0; r<4; r++){
        float ss = yv[0][r]*yv[0][r] + yv[1][r]*yv[1][r]
                 + yv[2][r]*yv[2][r] + yv[3][r]*yv[3][r];
        ss += __shfl_xor(ss, 1); ss += __shfl_xor(ss, 2);
        ss += __shfl_xor(ss, 4); ss += __shfl_xor(ss, 8);
        float rn = 1.f / fmaxf(sqrtf(ss), 1e-8f);
        #pragma unroll
        for (int nt=0; nt<4; nt++) yv[nt][r] *= rn;
      }
    }
    #pragma unroll
    for (int nt=0; nt<4; nt++){
      #pragma unroll
      for (int r=0; r<4; r++){
        int m = m0 + msub + mt*16 + kq*4 + r;
        int dd = nt*16 + mrow;
        int bq = m >> 9, l = m & 511;
        float y = yv[nt][r];
        if (s == 0)      Qh[((size_t)(bq*12 + h)*512 + l)*64 + dd] = (f16)y;
        else if (s == 1) Kh[((size_t)(bq*12 + h)*512 + l)*64 + dd] = (f16)y;
        else             Vt[((size_t)(bq*12 + h)*64 + dd)*512 + l] = (f16)y;
      }
    }
  }
}

// ---------- K3a: scores -> head-LN -> exp -> E (fp16, [b,h,i,j]) + rowsum partials ----------
// grid = b(16) x itile(32) x jtile(8) = 4096 blocks; single f16 LDS buffer, LN in place
__global__ __launch_bounds__(256) void k_scores(const f16* __restrict__ Qh,
    const f16* __restrict__ Kh, const void* __restrict__ gamma,
    const void* __restrict__ beta, const int* __restrict__ flag,
    f16* __restrict__ E, float* __restrict__ lsum){
  constexpr int TS = 72;
  __shared__ f16 S[12*16*TS];
  __shared__ float gL[12], beL[12];

  int tid = threadIdx.x;
  int w = tid >> 6, lane = tid & 63;
  int kq = lane >> 4, mrow = lane & 15;
  int bx = blockIdx.x;
  int jt = bx & 7, it = (bx >> 3) & 31, b = bx >> 8;
  int i0 = it*16, j0 = jt*64;

  if (tid < 12){ int isb = *flag; gL[tid] = ldf(gamma, tid, isb); beL[tid] = ldf(beta, tid, isb); }

  #pragma unroll
  for (int hh=0; hh<3; hh++){
    int h = w*3 + hh;
    const f16* kb = Kh + ((size_t)(b*12+h)*512 + i0 + mrow)*64;
    h8 a0 = *(const h8*)(kb + kq*8);
    h8 a1 = *(const h8*)(kb + 32 + kq*8);
    const f16* qb = Qh + ((size_t)(b*12+h)*512 + j0)*64;
    #pragma unroll
    for (int jn=0; jn<4; jn++){
      const f16* qr = qb + (size_t)(jn*16 + mrow)*64;
      h8 q0 = *(const h8*)(qr + kq*8);
      h8 q1 = *(const h8*)(qr + 32 + kq*8);
      f32x4 c = (f32x4){0.f,0.f,0.f,0.f};
      c = __builtin_amdgcn_mfma_f32_16x16x32_f16(a0, q0, c, 0, 0, 0);
      c = __builtin_amdgcn_mfma_f32_16x16x32_f16(a1, q1, c, 0, 0, 0);
      #pragma unroll
      for (int r=0;r<4;r++)
        S[(h*16 + kq*4 + r)*TS + jn*16 + mrow] = (f16)c[r];
    }
  }
  __syncthreads();
  int pj = tid & 63, piw = tid >> 6;
  #pragma unroll
  for (int p=0; p<4; p++){
    int i = piw*4 + p;
    float s[12];
    float mu = 0.f, sq = 0.f;
    #pragma unroll
    for (int h=0;h<12;h++){ s[h] = (float)S[(h*16+i)*TS + pj]; mu += s[h]; sq += s[h]*s[h]; }
    mu *= (1.f/12.f);
    float var = fmaxf(sq*(1.f/12.f) - mu*mu, 0.f);
    float rstd = rsqrtf(var + 1e-5f);
    #pragma unroll
    for (int h=0;h<12;h++){
      float e = __expf((s[h]-mu)*rstd*gL[h] + beL[h]);
      S[(h*16+i)*TS + pj] = (f16)e;
    }
  }
  __syncthreads();
  if (tid < 192){
    int h = tid >> 4, i = tid & 15;
    const f16* zr = &S[(h*16 + i)*TS];
    float ssum = 0.f;
    #pragma unroll
    for (int q=0;q<8;q++){
      h8 v = *(const h8*)(zr + q*8);
      #pragma unroll
      for (int t=0;t<8;t++) ssum += (float)v[t];
    }
    atomicAdd(&lsum[(size_t)(b*12+h)*512 + i0 + i], ssum);
  }
  #pragma unroll
  for (int u0=0; u0<6; u0++){
    int u = tid + u0*256;
    int h = u >> 7, rem = u & 127, i = rem >> 3, q = rem & 7;
    h8 v = *(const h8*)&S[(h*16 + i)*TS + q*8];
    *(h8*)(E + ((size_t)(b*12+h)*512 + i0 + i)*512 + j0 + q*8) = v;
  }
}

// ---------- K3b: PV MFMA from E, per-(b,h,itile); colsum via LDS; barrier-free K-loop ----------
__global__ __launch_bounds__(256) void k_pv2(const f16* __restrict__ E,
    const f16* __restrict__ Vt, const float* __restrict__ lsum,
    float* __restrict__ O, float* __restrict__ colsum){
  __shared__ float csL[512];
  int tid = threadIdx.x;
  int w = tid >> 6, lane = tid & 63;
  int kq = lane >> 4, mrow = lane & 15;
  int b = blockIdx.y;
  int h = blockIdx.x >> 3, it = blockIdx.x & 7;
  int i0w = it*64 + w*16;

  csL[tid] = 0.f; csL[tid + 256] = 0.f;
  float rinv = 1.f / lsum[(size_t)(b*12+h)*512 + i0w + mrow];
  __syncthreads();

  const f16* erow  = E  + ((size_t)(b*12+h)*512 + i0w + mrow)*512 + kq*8;
  const f16* vbase = Vt + ((size_t)(b*12+h)*64 + mrow)*512 + kq*8;

  f32x4 acc[4];
  #pragma unroll
  for (int nt=0; nt<4; nt++) acc[nt] = (f32x4){0.f,0.f,0.f,0.f};

  #pragma unroll 4
  for (int jt=0; jt<16; jt++){
    int j0 = jt*32;
    h8 ea  = *(const h8*)(erow + j0);
    h8 bf0 = *(const h8*)(vbase + j0);
    h8 bf1 = *(const h8*)(vbase + (size_t)16*512 + j0);
    h8 bf2 = *(const h8*)(vbase + (size_t)32*512 + j0);
    h8 bf3 = *(const h8*)(vbase + (size_t)48*512 + j0);
    acc[0] = __builtin_amdgcn_mfma_f32_16x16x32_f16(ea, bf0, acc[0], 0, 0, 0);
    acc[1] = __builtin_amdgcn_mfma_f32_16x16x32_f16(ea, bf1, acc[1], 0, 0, 0);
    acc[2] = __builtin_amdgcn_mfma_f32_16x16x32_f16(ea, bf2, acc[2], 0, 0, 0);
    acc[3] = __builtin_amdgcn_mfma_f32_16x16x32_f16(ea, bf3, acc[3], 0, 0, 0);
    float cs[8];
    #pragma unroll
    for (int t=0;t<8;t++) cs[t] = (float)ea[t] * rinv;
    #pragma unroll
    for (int t=0;t<8;t++){
      cs[t] += __shfl_xor(cs[t], 1); cs[t] += __shfl_xor(cs[t], 2);
      cs[t] += __shfl_xor(cs[t], 4); cs[t] += __shfl_xor(cs[t], 8);
    }
    if (mrow == 0){
      #pragma unroll
      for (int t=0;t<8;t++) atomicAdd(&csL[j0 + kq*8 + t], cs[t]);
    }
  }
  __syncthreads();
  atomicAdd(&colsum[b*512 + tid],       csL[tid]       * (1.f/12.f));
  atomicAdd(&colsum[b*512 + 256 + tid], csL[tid + 256] * (1.f/12.f));

  #pragma unroll
  for (int r=0; r<4; r++){
    float g = __shfl(rinv, kq*4 + r);
    #pragma unroll
    for (int nt=0; nt<4; nt++)
      O[((size_t)(b*512) + i0w + kq*4 + r)*768 + h*64 + nt*16 + mrow] = acc[nt][r] * g;
  }
}

// ---------- K4: merged probs: softmax(O @ Wout^T + bout), branch by blockIdx.y ----------
__global__ __launch_bounds__(256) void k_probs_m(const float* OA, const float* OB,
    const void* WoA, const void* WoB, const void* boA, const void* boB,
    float* prA, float* prB, const int* __restrict__ flag, int sbase){
  int z = sbase + blockIdx.y;
  const float* O = z ? OB : OA;
  const void* Wout = z ? WoB : WoA;
  const void* bout = z ? boB : boA;
  float* probs = z ? prB : prA;
  int isb = *flag;
  int tid = threadIdx.x, wv = tid>>6, lane = tid&63;
  int m = blockIdx.x*4 + wv;
  const float* orow = O + (size_t)m*768;
  float acc[20];
  #pragma unroll
  for (int c=0;c<20;c++) acc[c]=0.f;
  for (int kk=0; kk<12; kk++){
    float o = orow[kk*64 + lane];
    #pragma unroll
    for (int c=0;c<20;c++)
      acc[c] += o * ldf(Wout, c*768 + kk*64 + lane, isb);
  }
  #pragma unroll
  for (int c=0;c<20;c++){
    #pragma unroll
    for (int off=1; off<64; off<<=1) acc[c] += __shfl_xor(acc[c], off, 64);
  }
  float mx = -3.4e38f;
  #pragma unroll
  for (int c=0;c<20;c++){ acc[c] += ldf(bout, c, isb); mx = fmaxf(mx, acc[c]); }
  float s=0.f;
  #pragma unroll
  for (int c=0;c<20;c++){ acc[c] = __expf(acc[c]-mx); s += acc[c]; }
  float inv = 1.f/s;
  if (lane == 0){
    float* pr = probs + (size_t)m*20;
    #pragma unroll
    for (int c=0;c<20;c++) pr[c] = acc[c]*inv;
  }
}

// ---------- K5: merged final: both branches' get_weights + weighted sum + output ----------
__global__ __launch_bounds__(512) void k_final_m(const int* __restrict__ ids,
    const float* __restrict__ cs0, const float* __restrict__ cs1,
    const float* __restrict__ pr0, const float* __restrict__ pr1,
    const int* __restrict__ flag, void* __restrict__ outp){
  __shared__ float red[8];
  __shared__ float bcast;
  __shared__ float pacc[8][20];
  __shared__ float osum[20];
  int b = blockIdx.x, tid = threadIdx.x;
  int wv = tid>>6, lane = tid&63;
  int msk = (ids[b*512+tid] != 0);
  for (int br=0; br<2; br++){
    const float* colsum = br ? cs1 : cs0;
    const float* probs  = br ? pr1 : pr0;
    float w = msk ? colsum[b*512+tid] : 0.f;
    float mx = w;
    #pragma unroll
    for (int off=1; off<64; off<<=1) mx = fmaxf(mx, __shfl_xor(mx, off, 64));
    if (lane==0) red[wv] = mx;
    __syncthreads();
    if (tid==0){ float m2 = red[0]; for (int k2=1;k2<8;k2++) m2 = fmaxf(m2, red[k2]); bcast = m2; }
    __syncthreads();
    float M = bcast;
    float e = __expf(w - M);
    float s = e;
    #pragma unroll
    for (int off=1; off<64; off<<=1) s += __shfl_xor(s, off, 64);
    if (lane==0) red[wv] = s;
    __syncthreads();
    if (tid==0){ float s2=0.f; for (int k2=0;k2<8;k2++) s2 += red[k2]; bcast = s2; }
    __syncthreads();
    float wn = e / bcast;
    float p[20];
    const float* pr = probs + ((size_t)b*512 + tid)*20;
    #pragma unroll
    for (int c=0;c<20;c++) p[c] = wn * pr[c];
    #pragma unroll
    for (int c=0;c<20;c++){
      #pragma unroll
      for (int off=1; off<64; off<<=1) p[c] += __shfl_xor(p[c], off, 64);
    }
    if (lane==0){
      #pragma unroll
      for (int c=0;c<20;c++) pacc[wv][c] = p[c];
    }
    __syncthreads();
    if (tid < 20){
      float s2 = 0.f;
      #pragma unroll
      for (int k2=0;k2<8;k2++) s2 += pacc[k2][tid];
      if (br == 0) osum[tid] = s2;
      else         osum[tid] += s2;
    }
    __syncthreads();
  }
  if (tid < 20){
    float v = osum[tid] * 0.5f;
    if (*flag) ((ushort*)outp)[b*20 + tid] = f2b(v);
    else       ((float*)outp)[b*20 + tid] = v;
  }
}

extern "C" void kernel_launch(void* const* d_in, const int* in_sizes, int n_in,
                              void* d_out, int out_size, void* d_ws, size_t ws_size,
                              hipStream_t stream){
  (void)in_sizes; (void)n_in; (void)out_size;
  const int*  ids = (const int*)d_in[0];
  const void* wvp = d_in[1];
  const void* emb = d_in[2];
  const void* Wt[2]  = {d_in[3], d_in[9]};
  const void* bt[2]  = {d_in[4], d_in[10]};
  const void* gm[2]  = {d_in[5], d_in[11]};
  const void* bet[2] = {d_in[6], d_in[12]};
  const void* Wo[2]  = {d_in[7], d_in[13]};
  const void* bo[2]  = {d_in[8], d_in[14]};

  char* p = (char*)d_ws;
  #define ALLOC(ty, name, cnt) ty* name = (ty*)p; p += sizeof(ty)*(size_t)(cnt)

  // ---- try BIG layout (dual buffers, 9 dispatches) ----
  p = (char*)d_ws;
  ALLOC(float, O0, 6291456);
  ALLOC(float, O1, 6291456);
  ALLOC(f16, Qh0, 6291456); ALLOC(f16, Kh0, 6291456); ALLOC(f16, Vt0, 6291456);
  ALLOC(f16, Qh1, 6291456); ALLOC(f16, Kh1, 6291456); ALLOC(f16, Vt1, 6291456);
  ALLOC(f16, Ah0, 6291456); ALLOC(f16, Wh0, 1769472);
  ALLOC(f16, Ah1, 2621440); ALLOC(f16, Wh1, 737280);
  ALLOC(float, probs0, 163840); ALLOC(float, probs1, 163840);
  ALLOC(float, zb_big, 212992);   // colsum0, colsum1, lsum0, lsum1
  ALLOC(int, flag_big, 4);
  ALLOC(f16, E_big, 50331648);
  size_t needBig = (size_t)(p - (char*)d_ws);

  if (ws_size >= needBig){
    float* colsum0 = zb_big;          float* colsum1 = zb_big + 8192;
    float* lsum0   = zb_big + 16384;  float* lsum1   = zb_big + 16384 + 98304;
    int* flagp = flag_big; f16* E = E_big;

    k_init<<<833, 256, 0, stream>>>((const ushort*)wvp, flagp, zb_big);
    k_prep_all<<<3072+864+1280+360, 256, 0, stream>>>(ids, emb, wvp, Wt[0], Wt[1],
        flagp, Ah0, Wh0, Ah1, Wh1, 3072, 864, 1280, 360);
    dim3 gg(64, 18, 2);
    k_gemm_m<<<gg, 256, 0, stream>>>(Ah0, Wh0, bt[0], 768, Qh0, Kh0, Vt0,
                                     Ah1, Wh1, bt[1], 320, Qh1, Kh1, Vt1, flagp, 0);
    dim3 gpv(96, 16);
    k_scores<<<4096, 256, 0, stream>>>(Qh0, Kh0, gm[0], bet[0], flagp, E, lsum0);
    k_pv2<<<gpv, 256, 0, stream>>>(E, Vt0, lsum0, O0, colsum0);
    k_scores<<<4096, 256, 0, stream>>>(Qh1, Kh1, gm[1], bet[1], flagp, E, lsum1);
    k_pv2<<<gpv, 256, 0, stream>>>(E, Vt1, lsum1, O1, colsum1);
    dim3 gpr(2048, 2);
    k_probs_m<<<gpr, 256, 0, stream>>>(O0, O1, Wo[0], Wo[1], bo[0], bo[1],
                                       probs0, probs1, flagp, 0);
    k_final_m<<<16, 512, 0, stream>>>(ids, colsum0, colsum1, probs0, probs1, flagp, d_out);
    return;
  }

  // ---- MID layout (shared big buffers, 12 dispatches; fits in round-8-sized ws) ----
  p = (char*)d_ws;
  ALLOC(float, O, 6291456);
  ALLOC(f16, Qh, 6291456); ALLOC(f16, Kh, 6291456); ALLOC(f16, Vt, 6291456);
  ALLOC(f16, Ah, 6291456); ALLOC(f16, Wh, 1769472);
  ALLOC(float, probsA, 163840); ALLOC(float, probsB, 163840);
  ALLOC(float, zb, 212992);
  ALLOC(int, flagm, 4);
  ALLOC(f16, Em, 50331648);
  float* colsum0 = zb;          float* colsum1 = zb + 8192;
  float* lsum0   = zb + 16384;  float* lsum1   = zb + 16384 + 98304;

  k_init<<<833, 256, 0, stream>>>((const ushort*)wvp, flagm, zb);
  // branch 0
  k_prep_all<<<3072+864, 256, 0, stream>>>(ids, emb, wvp, Wt[0], Wt[1],
      flagm, Ah, Wh, Ah, Wh, 3072, 864, 0, 0);
  dim3 g1(64, 18, 1);
  k_gemm_m<<<g1, 256, 0, stream>>>(Ah, Wh, bt[0], 768, Qh, Kh, Vt,
                                   Ah, Wh, bt[0], 768, Qh, Kh, Vt, flagm, 0);
  dim3 gpv(96, 16);
  k_scores<<<4096, 256, 0, stream>>>(Qh, Kh, gm[0], bet[0], flagm, Em, lsum0);
  k_pv2<<<gpv, 256, 0, stream>>>(Em, Vt, lsum0, O, colsum0);
  dim3 gpr(2048, 1);
  k_probs_m<<<gpr, 256, 0, stream>>>(O, O, Wo[0], Wo[1], bo[0], bo[1],
                                     probsA, probsB, flagm, 0);
  // branch 1 (reuse Ah/Wh/QKV/O)
  k_prep_all<<<1280+360, 256, 0, stream>>>(ids, emb, wvp, Wt[0], Wt[1],
      flagm, Ah, Wh, Ah, Wh, 0, 0, 1280, 360);
  k_gemm_m<<<g1, 256, 0, stream>>>(Ah, Wh, bt[1], 320, Qh, Kh, Vt,
                                   Ah, Wh, bt[1], 320, Qh, Kh, Vt, flagm, 0);
  k_scores<<<4096, 256, 0, stream>>>(Qh, Kh, gm[1], bet[1], flagm, Em, lsum1);
  k_pv2<<<gpv, 256, 0, stream>>>(Em, Vt, lsum1, O, colsum1);
  k_probs_m<<<gpr, 256, 0, stream>>>(O, O, Wo[0], Wo[1], bo[0], bo[1],
                                     probsA, probsB, flagm, 1);
  k_final_m<<<16, 512, 0, stream>>>(ids, colsum0, colsum1, probsA, probsB, flagm, d_out);
  #undef ALLOC
}